// Round 8
// baseline (423.939 us; speedup 1.0000x reference)
//
#include <hip/hip_runtime.h>
#include <cstdint>
#include <cstddef>

// Problem constants (reference: B=256, T=256, D=512, H=8, hd=64)
#define B_   256
#define T_   256
#define D_   512
#define H_   8
#define HD_  64
#define BT_  65536
#define KDIM 512

typedef __bf16 bf16x8_t __attribute__((ext_vector_type(8)));
typedef __bf16 bf16x4_t __attribute__((ext_vector_type(4)));
typedef float  f32x4_t  __attribute__((ext_vector_type(4)));

__device__ __forceinline__ void gload16(const void* gp, void* lp) {
  // async global->LDS, 16B per lane; LDS dest = wave-uniform base + lane*16
  __builtin_amdgcn_global_load_lds(
      (const __attribute__((address_space(1))) void*)gp,
      (__attribute__((address_space(3))) void*)lp, 16, 0, 0);
}

#define BAR()   __builtin_amdgcn_s_barrier()
#define SCB()   __builtin_amdgcn_sched_barrier(0)
#define LGKM0() asm volatile("s_waitcnt lgkmcnt(0)" ::: "memory")

// ---------------- fused prep: cast x, cast weights, rope tables ----------------
__global__ __launch_bounds__(256) void prep(
    const float* __restrict__ x,
    const float* __restrict__ wq, const float* __restrict__ wk,
    const float* __restrict__ wv, const float* __restrict__ wo,
    __bf16* __restrict__ xb, __bf16* __restrict__ wb,
    float* __restrict__ rc, float* __restrict__ rs) {
  const int b = blockIdx.x;
  if (b < 2048) {
    for (size_t i = (size_t)b * 256 + threadIdx.x; i < 8388608UL; i += 524288UL) {
      f32x4_t v = *(const f32x4_t*)&x[i * 4];
      bf16x4_t o;
      o[0] = (__bf16)v[0]; o[1] = (__bf16)v[1]; o[2] = (__bf16)v[2]; o[3] = (__bf16)v[3];
      *(bf16x4_t*)&xb[i * 4] = o;
    }
  } else if (b < 2304) {
    for (int i = (b - 2048) * 256 + threadIdx.x; i < 262144; i += 65536) {
      int which = i >> 16;
      int off   = (i & 65535) * 4;
      const float* src = (which == 0) ? wq : (which == 1) ? wk : (which == 2) ? wv : wo;
      f32x4_t v = *(const f32x4_t*)&src[off];
      bf16x4_t o;
      o[0] = (__bf16)v[0]; o[1] = (__bf16)v[1]; o[2] = (__bf16)v[2]; o[3] = (__bf16)v[3];
      *(bf16x4_t*)&wb[(size_t)which * 262144 + off] = o;
    }
  } else {
    int idx = (b - 2304) * 256 + threadIdx.x;
    if (idx < T_ * 32) {
      int t = idx >> 5, j = idx & 31;
      float inv = powf(10000.f, -(float)j * (1.0f / 32.0f));  // 10000^(-2j/64)
      float a = (float)t * inv;
      rc[idx] = cosf(a);
      rs[idx] = sinf(a);
    }
  }
}

// ---------------- 256x256 GEMM, BK=64, 8 waves, 8-phase, T2 swizzle, MULTI-JOB -
// Grid = 256 (one block per M-tile, 1/CU). Each block runs NJOBS sub-GEMMs
// (MODE 0: 6 = 3 z-pass x 2 N-tile; MODE 1: 2 N-tiles) over ONE continuous
// stage stream g=0..NJOBS*32-1 (job = g>>5 selects B panel; A restaged from L2).
// Fill once, drain once; epilogue between jobs is reg->global only (no LDS, no
// barrier). vmcnt(6)/K-tile stays valid: vmcnt retires in issue order, so
// interleaved epilogue stores only make the count stricter. Round-5 region<->
// reader race proof carries over (stage formula uniform across boundaries).
template <int MODE>
__global__ __launch_bounds__(512, 2) void gemm256(
    const __bf16* __restrict__ A, const __bf16* __restrict__ W,
    void* __restrict__ outp) {
  constexpr int NJOBS = (MODE == 0) ? 6 : 2;
  __shared__ __bf16 lds[65536];  // [dbuf2][mat2][256][64] bf16 = 128 KiB
  const int tid = threadIdx.x;
  const int lane = tid & 63, w = tid >> 6;
  const int wm = w >> 2, wn = w & 3;          // 2 x 4 waves
  const int l15 = lane & 15, lg = lane >> 4;
  const int swl = l15 & 7;                    // read-side swizzle key (== row&7)

  // XCD-aware swizzle (grid 256 = 8*32); by = M tile
  const int cpx = gridDim.x >> 3;
  const int swz = (blockIdx.x & 7) * cpx + (blockIdx.x >> 3);
  const int m0 = swz * 256;

  const __bf16* Ag = A + (size_t)m0 * KDIM;
  const int srow = tid >> 3;          // 0..63
  // inverse swizzle on global source (gload_lds dest must stay linear)
  const int scol = (((tid & 7) ^ ((tid >> 3) & 7)) * 8);

  // B panel byte offset for job j
#define BOFF(JB) ((MODE == 0) ? ((size_t)((JB) >> 1) * 262144 + (size_t)((JB) & 1) * 131072) \
                              : ((size_t)(JB) * 131072))

  // stage half-tile g: job=g>>5, local tile Tl=(g>>2)&7, region r=g&3
  // (0:A.h0 1:B.h0 2:B.h1 3:A.h1), parity P=(g>>2)&1
#define STAGE(J) do {                                                        \
    const int jb__ = (J) >> 5;                                               \
    const int Tl__ = ((J) >> 2) & 7, r__ = (J) & 3;                          \
    const int h__ = r__ >> 1;                                                \
    const int isB__ = (r__ == 1 || r__ == 2);                                \
    const size_t grow__ = (size_t)(h__ * 128 + srow) * KDIM + Tl__ * 64 + scol; \
    const __bf16* gp__ = isB__ ? (W + BOFF(jb__) + grow__) : (Ag + grow__);  \
    __bf16* lp__ = &lds[(((J) >> 2) & 1) * 32768 + isB__ * 16384 + (h__ * 128 + w * 8) * 64]; \
    gload16(gp__, lp__);                                                     \
    gload16(gp__ + 64 * KDIM, lp__ + 64 * 64);                               \
  } while (0)

  f32x4_t acc[8][4];
#pragma unroll
  for (int i = 0; i < 8; i++)
#pragma unroll
    for (int j = 0; j < 4; j++) acc[i][j] = (f32x4_t){0.f, 0.f, 0.f, 0.f};

  bf16x8_t a0[4][2], a1[4][2], b0[2][2], b1[2][2];

#define PH_A(P, STJ) do {                                                    \
    const int ab__ = (P) * 32768;                                            \
    _Pragma("unroll") for (int i = 0; i < 4; i++)                            \
      _Pragma("unroll") for (int s = 0; s < 2; s++)                          \
        a0[i][s] = *(const bf16x8_t*)&lds[ab__ + (wm * 64 + i * 16 + l15) * 64 + (((s * 4 + lg) ^ swl) << 3)]; \
    _Pragma("unroll") for (int j = 0; j < 2; j++)                            \
      _Pragma("unroll") for (int s = 0; s < 2; s++)                          \
        b0[j][s] = *(const bf16x8_t*)&lds[ab__ + 16384 + (wn * 32 + j * 16 + l15) * 64 + (((s * 4 + lg) ^ swl) << 3)]; \
    if ((STJ) >= 0) STAGE(STJ);                                              \
    SCB(); BAR(); LGKM0(); SCB();                                            \
    __builtin_amdgcn_s_setprio(1);                                           \
    _Pragma("unroll") for (int i = 0; i < 4; i++)                            \
      _Pragma("unroll") for (int j = 0; j < 2; j++) {                        \
        acc[i][j] = __builtin_amdgcn_mfma_f32_16x16x32_bf16(a0[i][0], b0[j][0], acc[i][j], 0, 0, 0); \
        acc[i][j] = __builtin_amdgcn_mfma_f32_16x16x32_bf16(a0[i][1], b0[j][1], acc[i][j], 0, 0, 0); \
      }                                                                      \
    __builtin_amdgcn_s_setprio(0); SCB(); BAR();                             \
  } while (0)

#define PH_B(P, STJ) do {                                                    \
    const int ab__ = (P) * 32768;                                            \
    _Pragma("unroll") for (int j = 0; j < 2; j++)                            \
      _Pragma("unroll") for (int s = 0; s < 2; s++)                          \
        b1[j][s] = *(const bf16x8_t*)&lds[ab__ + 16384 + (128 + wn * 32 + j * 16 + l15) * 64 + (((s * 4 + lg) ^ swl) << 3)]; \
    if ((STJ) >= 0) STAGE(STJ);                                              \
    SCB(); BAR(); LGKM0(); SCB();                                            \
    __builtin_amdgcn_s_setprio(1);                                           \
    _Pragma("unroll") for (int i = 0; i < 4; i++)                            \
      _Pragma("unroll") for (int j = 0; j < 2; j++) {                        \
        acc[i][j + 2] = __builtin_amdgcn_mfma_f32_16x16x32_bf16(a0[i][0], b1[j][0], acc[i][j + 2], 0, 0, 0); \
        acc[i][j + 2] = __builtin_amdgcn_mfma_f32_16x16x32_bf16(a0[i][1], b1[j][1], acc[i][j + 2], 0, 0, 0); \
      }                                                                      \
    __builtin_amdgcn_s_setprio(0); SCB(); BAR();                             \
  } while (0)

#define PH_C(P, STJ) do {                                                    \
    const int ab__ = (P) * 32768;                                            \
    _Pragma("unroll") for (int i = 0; i < 4; i++)                            \
      _Pragma("unroll") for (int s = 0; s < 2; s++)                          \
        a1[i][s] = *(const bf16x8_t*)&lds[ab__ + (128 + wm * 64 + i * 16 + l15) * 64 + (((s * 4 + lg) ^ swl) << 3)]; \
    if ((STJ) >= 0) STAGE(STJ);                                              \
    SCB(); BAR(); LGKM0(); SCB();                                            \
    __builtin_amdgcn_s_setprio(1);                                           \
    _Pragma("unroll") for (int i = 0; i < 4; i++)                            \
      _Pragma("unroll") for (int j = 0; j < 2; j++) {                        \
        acc[i + 4][j + 2] = __builtin_amdgcn_mfma_f32_16x16x32_bf16(a1[i][0], b1[j][0], acc[i + 4][j + 2], 0, 0, 0); \
        acc[i + 4][j + 2] = __builtin_amdgcn_mfma_f32_16x16x32_bf16(a1[i][1], b1[j][1], acc[i + 4][j + 2], 0, 0, 0); \
      }                                                                      \
    __builtin_amdgcn_s_setprio(0); SCB(); BAR();                             \
  } while (0)

#define PH_D(P, STJ, VM) do {                                                \
    if ((STJ) >= 0) STAGE(STJ);                                              \
    SCB(); BAR();                                                            \
    __builtin_amdgcn_s_setprio(1);                                           \
    _Pragma("unroll") for (int i = 0; i < 4; i++)                            \
      _Pragma("unroll") for (int j = 0; j < 2; j++) {                        \
        acc[i + 4][j] = __builtin_amdgcn_mfma_f32_16x16x32_bf16(a1[i][0], b0[j][0], acc[i + 4][j], 0, 0, 0); \
        acc[i + 4][j] = __builtin_amdgcn_mfma_f32_16x16x32_bf16(a1[i][1], b0[j][1], acc[i + 4][j], 0, 0, 0); \
      }                                                                      \
    __builtin_amdgcn_s_setprio(0);                                           \
    if ((VM) == 6) asm volatile("s_waitcnt vmcnt(6)" ::: "memory");          \
    else if ((VM) == 0) asm volatile("s_waitcnt vmcnt(0)" ::: "memory");     \
    SCB(); BAR();                                                            \
  } while (0)

  // prologue: stage S0..S6 (tile0 complete + tile1 r0,r1,r2)
  STAGE(0); STAGE(1); STAGE(2); STAGE(3); STAGE(4); STAGE(5); STAGE(6);
  asm volatile("s_waitcnt vmcnt(6)" ::: "memory");  // tile0 landed
  SCB(); BAR();

#pragma unroll 1
  for (int jb = 0; jb < NJOBS; ++jb) {
    if (jb < NJOBS - 1) {
      // full-pipeline job: 4 tile-pairs, stages keep flowing (lead 7)
#pragma unroll 1
      for (int tp = 0; tp < 4; ++tp) {
        const int g0 = jb * 32 + tp * 8;
        PH_A(0, g0 + 7);  PH_B(0, g0 + 8);  PH_C(0, g0 + 9);  PH_D(0, g0 + 10, 6);
        PH_A(1, g0 + 11); PH_B(1, g0 + 12); PH_C(1, g0 + 13); PH_D(1, g0 + 14, 6);
      }
    } else {
      // tail job: 3 pairs + peeled last 2 tiles with drain
#pragma unroll 1
      for (int tp = 0; tp < 3; ++tp) {
        const int g0 = jb * 32 + tp * 8;
        PH_A(0, g0 + 7);  PH_B(0, g0 + 8);  PH_C(0, g0 + 9);  PH_D(0, g0 + 10, 6);
        PH_A(1, g0 + 11); PH_B(1, g0 + 12); PH_C(1, g0 + 13); PH_D(1, g0 + 14, 6);
      }
      PH_A(0, jb * 32 + 31); PH_B(0, -1); PH_C(0, -1); PH_D(0, -1, 0);
      PH_A(1, -1); PH_B(1, -1); PH_C(1, -1); PH_D(1, -1, -1);
    }

    // ---- epilogue for job jb (reg->global only; no LDS, no barrier) ----
    // C/D layout col=lane&15, row=(lane>>4)*4+reg  [m89-verified]
    {
      const int n0j = (MODE == 0) ? ((jb & 1) * 256) : (jb * 256);
#pragma unroll
      for (int i = 0; i < 8; i++) {
#pragma unroll
        for (int rr = 0; rr < 4; rr++) {
          const int m = m0 + (i >> 2) * 128 + wm * 64 + (i & 3) * 16 + lg * 4 + rr;
          if (MODE == 0) {
            __bf16* outz = (__bf16*)outp + (size_t)(jb >> 1) * ((size_t)BT_ * D_);
            const int bb = m >> 8, tt = m & 255;
            const size_t rbase = ((size_t)bb * H_) * T_ * HD_ + (size_t)tt * HD_;
#pragma unroll
            for (int j = 0; j < 4; j++) {
              const int c = n0j + (j >> 1) * 128 + wn * 32 + (j & 1) * 16 + l15;
              const int hh = c >> 6, dd = c & 63;
              outz[rbase + (size_t)hh * (T_ * HD_) + dd] = (__bf16)acc[i][j][rr];
            }
          } else {
            float* outf = (float*)outp;
#pragma unroll
            for (int j = 0; j < 4; j++) {
              const int c = n0j + (j >> 1) * 128 + wn * 32 + (j & 1) * 16 + l15;
              outf[(size_t)m * D_ + c] = acc[i][j][rr];
            }
          }
        }
      }
      // reset accumulators for next job
#pragma unroll
      for (int i = 0; i < 8; i++)
#pragma unroll
        for (int j = 0; j < 4; j++) acc[i][j] = (f32x4_t){0.f, 0.f, 0.f, 0.f};
    }
  }

#undef PH_A
#undef PH_B
#undef PH_C
#undef PH_D
#undef STAGE
#undef BOFF
}

// ---------------- in-place RMSNorm + RoPE on Q and K (HBM-roofline) ----------
__global__ __launch_bounds__(256) void norm_rope(
    __bf16* __restrict__ qb, __bf16* __restrict__ kb,
    const float* __restrict__ gq, const float* __restrict__ gk,
    const float* __restrict__ rc, const float* __restrict__ rs) {
  const int gid = blockIdx.x * 256 + threadIdx.x;
  const int wid = gid >> 6;
  const int lane = gid & 63;
  const int l2 = lane & 31;
  const int half = lane >> 5;
  const int nw = (gridDim.x * 256) >> 6;
  const int NROWS = B_ * H_ * T_;
  for (int idx = wid; idx < NROWS; idx += nw) {
    int ri = idx * 2 + half;
    int isk = ri >= NROWS;
    int r = isk ? ri - NROWS : ri;
    __bf16* base = isk ? kb : qb;
    const float* g = isk ? gk : gq;
    size_t off = (size_t)r * HD_ + 2 * l2;
    unsigned u = *(const unsigned*)&base[off];
    float v0 = (float)__builtin_bit_cast(__bf16, (unsigned short)(u & 0xffffu));
    float v1 = (float)__builtin_bit_cast(__bf16, (unsigned short)(u >> 16));
    float ss = v0 * v0 + v1 * v1;
#pragma unroll
    for (int m = 1; m < 32; m <<= 1) ss += __shfl_xor(ss, m);
    float rn = rsqrtf(ss * (1.0f / HD_) + 1e-6f);
    v0 *= rn * g[2 * l2];
    v1 *= rn * g[2 * l2 + 1];
    int t = r & (T_ - 1);
    int j0 = (2 * l2) & 31;
    float c0 = rc[t * 32 + j0], c1 = rc[t * 32 + j0 + 1];
    float s0 = rs[t * 32 + j0], s1 = rs[t * 32 + j0 + 1];
    float p0 = __shfl_xor(v0, 16);
    float p1 = __shfl_xor(v1, 16);
    float sg = (l2 < 16) ? -1.f : 1.f;
    float o0 = v0 * c0 + sg * p0 * s0;
    float o1 = v1 * c1 + sg * p1 * s1;
    unsigned short h0 = __builtin_bit_cast(unsigned short, (__bf16)o0);
    unsigned short h1 = __builtin_bit_cast(unsigned short, (__bf16)o1);
    *(unsigned*)&base[off] = (unsigned)h0 | ((unsigned)h1 << 16);
  }
}

// ---------------- attention v2: 80KB LDS -> 2 blocks/CU, chunked PV ----------
// (round-7 verified) One block per (b,h), 8 balanced waves, fixed-shift softmax.
__global__ __launch_bounds__(512, 2) void attn_kernel(
    const __bf16* __restrict__ qb, const __bf16* __restrict__ kb,
    const __bf16* __restrict__ vb, __bf16* __restrict__ ob) {
  __shared__ __bf16 Kl[256 * 64];   // 32 KB
  __shared__ __bf16 VT[64 * 256];   // 32 KB (V transposed, d-major)
  __shared__ __bf16 Pl[8 * 16 * 64];// 16 KB (per-wave 64-key chunk)
  const int bh = blockIdx.x;
  const __bf16* Qg = qb + (size_t)bh * (T_ * HD_);
  const __bf16* Kg = kb + (size_t)bh * (T_ * HD_);
  const __bf16* Vg = vb + (size_t)bh * (T_ * HD_);
  const int tid = threadIdx.x, lane = tid & 63, w = tid >> 6;
  const int bI = bh >> 3, hI = bh & 7;

#pragma unroll
  for (int p = 0; p < 4; p++) {
    const int t = p * 64 + (tid >> 3);
    const int a = tid & 7;
    const int d0 = a * 8;
    *(bf16x8_t*)&Kl[t * 64 + (((a ^ (t & 7)) << 3))] =
        *(const bf16x8_t*)&Kg[t * HD_ + d0];
    bf16x8_t vv = *(const bf16x8_t*)&Vg[t * HD_ + d0];
#pragma unroll
    for (int j = 0; j < 8; j++) {
      const int row = d0 + j;                       // V d-dim
      const int rk = (row & 7) ^ ((row >> 3) & 7);
      VT[row * 256 + (((t >> 3) ^ rk) << 3) + (t & 7)] = vv[j];
    }
  }
  __syncthreads();

  const int l15 = lane & 15;
  const int lg = lane >> 4;
  const int sw = l15 & 7;
  const f32x4_t zero = {0.f, 0.f, 0.f, 0.f};
  const float C1 = 0.0072134752f;      // 0.125 * 0.04 * log2(e)
  const float LOG2E = 1.44269504f;

  for (int half = 0; half < 2; half++) {
    const int qt = half ? (15 - w) : w;   // balanced: every wave ~18 even-tiles
    const int q0 = qt * 16;
    bf16x8_t aq0 = *(const bf16x8_t*)&Qg[(q0 + l15) * HD_ + lg * 8];
    bf16x8_t aq1 = *(const bf16x8_t*)&Qg[(q0 + l15) * HD_ + 32 + lg * 8];
    const int ntiles_e = (qt + 2) & ~1;
    const int qr = q0 + (lg << 2);

    f32x4_t ls = {0.f, 0.f, 0.f, 0.f};
    f32x4_t o[4];
#pragma unroll
    for (int j = 0; j < 4; j++) o[j] = zero;

    for (int t0 = 0; t0 < ntiles_e; t0 += 4) {     // 64-key chunks
      const int te = (t0 + 4 < ntiles_e) ? (t0 + 4) : ntiles_e;
      for (int n = t0; n < te; ++n) {
        bf16x8_t kb0 = *(const bf16x8_t*)&Kl[(n * 16 + l15) * 64 + ((lg ^ sw) << 3)];
        bf16x8_t kb1 = *(const bf16x8_t*)&Kl[(n * 16 + l15) * 64 + (((4 + lg) ^ sw) << 3)];
        f32x4_t a = __builtin_amdgcn_mfma_f32_16x16x32_bf16(aq0, kb0, zero, 0, 0, 0);
        a = __builtin_amdgcn_mfma_f32_16x16x32_bf16(aq1, kb1, a, 0, 0, 0);
        const int key = n * 16 + l15;
        const int lsl = ((n - t0) << 1) + (l15 >> 3);   // chunk-local slot
#pragma unroll
        for (int r = 0; r < 4; r++) {
          float e2 = __builtin_amdgcn_exp2f(a[r] * C1);
          float cm = -100.f * __builtin_amdgcn_rcpf(e2 + 1.f);  // cap - 50
          float p = __builtin_amdgcn_exp2f(cm * LOG2E);
          p = (key <= qr + r) ? p : 0.f;
          ls[r] += p;
          const int ro = (lg << 2) + r;
          Pl[w * 1024 + ro * 64 + ((lsl ^ (ro & 7)) << 3) + (l15 & 7)] = (__bf16)p;
        }
      }
      asm volatile("s_waitcnt lgkmcnt(0)" ::: "memory");
      __builtin_amdgcn_sched_barrier(0);
      const int nkc = (te - t0) >> 1;
      for (int kcc = 0; kcc < nkc; ++kcc) {
        bf16x8_t pa = *(const bf16x8_t*)&Pl[w * 1024 + l15 * 64 + (((kcc * 4 + lg) ^ sw) << 3)];
#pragma unroll
        for (int j = 0; j < 4; j++) {
          const int row = j * 16 + l15;
          const int rk = sw ^ ((2 * j + (l15 >> 3)) & 7);   // VT key for this row
          const int sl = (t0 << 1) + kcc * 4 + lg;          // global 16B slot
          bf16x8_t bv = *(const bf16x8_t*)&VT[row * 256 + ((sl ^ rk) << 3)];
          o[j] = __builtin_amdgcn_mfma_f32_16x16x32_bf16(pa, bv, o[j], 0, 0, 0);
        }
      }
    }

#pragma unroll
    for (int off = 1; off < 16; off <<= 1) {
#pragma unroll
      for (int r = 0; r < 4; r++) ls[r] += __shfl_xor(ls[r], off);
    }

    float rl[4];
#pragma unroll
    for (int r = 0; r < 4; r++) rl[r] = 1.0f / ls[r];
#pragma unroll
    for (int j = 0; j < 4; j++) {
      int dd = j * 16 + l15;
#pragma unroll
      for (int r = 0; r < 4; r++) {
        int q = qr + r;
        ob[((size_t)(bI * T_ + q)) * D_ + hI * HD_ + dd] = (__bf16)(o[j][r] * rl[r]);
      }
    }
  }
}

// ---------------- launch ----------------
extern "C" void kernel_launch(void* const* d_in, const int* in_sizes, int n_in,
                              void* d_out, int out_size, void* d_ws, size_t ws_size,
                              hipStream_t stream) {
  (void)in_sizes; (void)n_in; (void)out_size; (void)ws_size;
  const float* x  = (const float*)d_in[0];
  const float* wq = (const float*)d_in[1];
  const float* wk = (const float*)d_in[2];
  const float* wv = (const float*)d_in[3];
  const float* wo = (const float*)d_in[4];
  const float* gq = (const float*)d_in[5];
  const float* gk = (const float*)d_in[6];

  // ws layout (bytes): xb 64MB (aliased by attn-out) | q 64MB | k 64MB | v 64MB | w 2MB | rope 64KB
  char* ws = (char*)d_ws;
  __bf16* xb   = (__bf16*)ws;
  __bf16* qkvb = (__bf16*)(ws + 67108864UL);
  __bf16* qb = qkvb;
  __bf16* kb = qkvb + 33554432UL;
  __bf16* vb = qkvb + 67108864UL;
  __bf16* wb = (__bf16*)(ws + 4UL * 67108864UL);
  float*  rc = (float*)(ws + 4UL * 67108864UL + 2097152UL);
  float*  rs = rc + 8192;
  __bf16* ob = xb;  // alias: xb dead after QKV GEMM

  prep<<<dim3(2336), 256, 0, stream>>>(x, wq, wk, wv, wo, xb, wb, rc, rs);
  gemm256<0><<<dim3(256), 512, 0, stream>>>(xb, wb, (void*)qkvb);
  norm_rope<<<dim3(2048), 256, 0, stream>>>(qb, kb, gq, gk, rc, rs);
  attn_kernel<<<dim3(2048), 512, 0, stream>>>(qb, kb, vb, ob);
  gemm256<1><<<dim3(256), 512, 0, stream>>>(ob, wb + 3UL * 262144UL, d_out);
}

// Round 9
// 303.760 us; speedup vs baseline: 1.3956x; 1.3956x over previous
//
#include <hip/hip_runtime.h>
#include <cstdint>
#include <cstddef>

// Problem constants (reference: B=256, T=256, D=512, H=8, hd=64)
#define B_   256
#define T_   256
#define D_   512
#define H_   8
#define HD_  64
#define BT_  65536
#define KDIM 512

typedef __bf16 bf16x8_t __attribute__((ext_vector_type(8)));
typedef __bf16 bf16x4_t __attribute__((ext_vector_type(4)));
typedef float  f32x4_t  __attribute__((ext_vector_type(4)));

__device__ __forceinline__ void gload16(const void* gp, void* lp) {
  // async global->LDS, 16B per lane; LDS dest = wave-uniform base + lane*16
  __builtin_amdgcn_global_load_lds(
      (const __attribute__((address_space(1))) void*)gp,
      (__attribute__((address_space(3))) void*)lp, 16, 0, 0);
}

#define BAR()   __builtin_amdgcn_s_barrier()
#define SCB()   __builtin_amdgcn_sched_barrier(0)
#define LGKM0() asm volatile("s_waitcnt lgkmcnt(0)" ::: "memory")

// ---------------- fused prep: cast x, cast weights, rope tables ----------------
__global__ __launch_bounds__(256) void prep(
    const float* __restrict__ x,
    const float* __restrict__ wq, const float* __restrict__ wk,
    const float* __restrict__ wv, const float* __restrict__ wo,
    __bf16* __restrict__ xb, __bf16* __restrict__ wb,
    float* __restrict__ rc, float* __restrict__ rs) {
  const int b = blockIdx.x;
  if (b < 2048) {
    for (size_t i = (size_t)b * 256 + threadIdx.x; i < 8388608UL; i += 524288UL) {
      f32x4_t v = *(const f32x4_t*)&x[i * 4];
      bf16x4_t o;
      o[0] = (__bf16)v[0]; o[1] = (__bf16)v[1]; o[2] = (__bf16)v[2]; o[3] = (__bf16)v[3];
      *(bf16x4_t*)&xb[i * 4] = o;
    }
  } else if (b < 2304) {
    for (int i = (b - 2048) * 256 + threadIdx.x; i < 262144; i += 65536) {
      int which = i >> 16;
      int off   = (i & 65535) * 4;
      const float* src = (which == 0) ? wq : (which == 1) ? wk : (which == 2) ? wv : wo;
      f32x4_t v = *(const f32x4_t*)&src[off];
      bf16x4_t o;
      o[0] = (__bf16)v[0]; o[1] = (__bf16)v[1]; o[2] = (__bf16)v[2]; o[3] = (__bf16)v[3];
      *(bf16x4_t*)&wb[(size_t)which * 262144 + off] = o;
    }
  } else {
    int idx = (b - 2304) * 256 + threadIdx.x;
    if (idx < T_ * 32) {
      int t = idx >> 5, j = idx & 31;
      float inv = powf(10000.f, -(float)j * (1.0f / 32.0f));  // 10000^(-2j/64)
      float a = (float)t * inv;
      rc[idx] = cosf(a);
      rs[idx] = sinf(a);
    }
  }
}

// ---------------- 256x256 GEMM, BK=64, 8 waves, 8-phase schedule, T2 swizzle --
// (round-7 verified structure; round-9 change: z/N-fastest tile decode so 6
// temporally-adjacent blocks on one XCD share an A-panel via L2)
// MODE 0: 3 z-passes (Q,K,V), bf16 scatter to (B,H,T,hd), grid 1536.
// MODE 1: single pass, f32 row-major (m,512), grid 512.
template <int MODE>
__global__ __launch_bounds__(512, 2) void gemm256(
    const __bf16* __restrict__ A, const __bf16* __restrict__ W,
    void* __restrict__ outp) {
  __shared__ __bf16 lds[65536];  // [dbuf2][mat2][256][64] bf16 = 128 KiB
  const int tid = threadIdx.x;
  const int lane = tid & 63, w = tid >> 6;
  const int wm = w >> 2, wn = w & 3;          // 2 x 4 waves
  const int l15 = lane & 15, lg = lane >> 4;
  const int swl = l15 & 7;                    // read-side swizzle key (== row&7)

  // XCD-aware swizzle (grid % 8 == 0; 1536 or 512)
  const int cpx = gridDim.x >> 3;
  const int swz = (blockIdx.x & 7) * cpx + (blockIdx.x >> 3);
  // z/N fastest: consecutive swz (same XCD chunk) share the A-panel
  int m_idx, bz, bx;
  if (MODE == 0) {
    m_idx = swz / 6;
    const int rem = swz - m_idx * 6;
    bz = rem >> 1;
    bx = rem & 1;
  } else {
    m_idx = swz >> 1;
    bz = 0;
    bx = swz & 1;
  }
  const int m0 = m_idx * 256, n0 = bx * 256;

  const __bf16* Ag = A + (size_t)m0 * KDIM;
  const __bf16* Bg = W + (size_t)bz * (KDIM * KDIM) + (size_t)n0 * KDIM;
  const int srow = tid >> 3;          // 0..63
  // inverse swizzle on global source (gload_lds dest must stay linear)
  const int scol = (((tid & 7) ^ ((tid >> 3) & 7)) * 8);

#define STAGE(J) do {                                                        \
    const int T__ = (J) >> 2, r__ = (J) & 3;                                 \
    const int h__ = r__ >> 1;                                                \
    const int isB__ = (r__ == 1 || r__ == 2);                                \
    const size_t grow__ = (size_t)(h__ * 128 + srow) * KDIM + T__ * 64 + scol; \
    const __bf16* gp__ = isB__ ? (Bg + grow__) : (Ag + grow__);              \
    __bf16* lp__ = &lds[(T__ & 1) * 32768 + isB__ * 16384 + (h__ * 128 + w * 8) * 64]; \
    gload16(gp__, lp__);                                                     \
    gload16(gp__ + 64 * KDIM, lp__ + 64 * 64);                               \
  } while (0)

  f32x4_t acc[8][4];
#pragma unroll
  for (int i = 0; i < 8; i++)
#pragma unroll
    for (int j = 0; j < 4; j++) acc[i][j] = (f32x4_t){0.f, 0.f, 0.f, 0.f};

  bf16x8_t a0[4][2], a1[4][2], b0[2][2], b1[2][2];

#define PH_A(P, STJ) do {                                                    \
    const int ab__ = (P) * 32768;                                            \
    _Pragma("unroll") for (int i = 0; i < 4; i++)                            \
      _Pragma("unroll") for (int s = 0; s < 2; s++)                          \
        a0[i][s] = *(const bf16x8_t*)&lds[ab__ + (wm * 64 + i * 16 + l15) * 64 + (((s * 4 + lg) ^ swl) << 3)]; \
    _Pragma("unroll") for (int j = 0; j < 2; j++)                            \
      _Pragma("unroll") for (int s = 0; s < 2; s++)                          \
        b0[j][s] = *(const bf16x8_t*)&lds[ab__ + 16384 + (wn * 32 + j * 16 + l15) * 64 + (((s * 4 + lg) ^ swl) << 3)]; \
    if ((STJ) >= 0) STAGE(STJ);                                              \
    SCB(); BAR(); LGKM0(); SCB();                                            \
    __builtin_amdgcn_s_setprio(1);                                           \
    _Pragma("unroll") for (int i = 0; i < 4; i++)                            \
      _Pragma("unroll") for (int j = 0; j < 2; j++) {                        \
        acc[i][j] = __builtin_amdgcn_mfma_f32_16x16x32_bf16(a0[i][0], b0[j][0], acc[i][j], 0, 0, 0); \
        acc[i][j] = __builtin_amdgcn_mfma_f32_16x16x32_bf16(a0[i][1], b0[j][1], acc[i][j], 0, 0, 0); \
      }                                                                      \
    __builtin_amdgcn_s_setprio(0); SCB(); BAR();                             \
  } while (0)

#define PH_B(P, STJ) do {                                                    \
    const int ab__ = (P) * 32768;                                            \
    _Pragma("unroll") for (int j = 0; j < 2; j++)                            \
      _Pragma("unroll") for (int s = 0; s < 2; s++)                          \
        b1[j][s] = *(const bf16x8_t*)&lds[ab__ + 16384 + (128 + wn * 32 + j * 16 + l15) * 64 + (((s * 4 + lg) ^ swl) << 3)]; \
    if ((STJ) >= 0) STAGE(STJ);                                              \
    SCB(); BAR(); LGKM0(); SCB();                                            \
    __builtin_amdgcn_s_setprio(1);                                           \
    _Pragma("unroll") for (int i = 0; i < 4; i++)                            \
      _Pragma("unroll") for (int j = 0; j < 2; j++) {                        \
        acc[i][j + 2] = __builtin_amdgcn_mfma_f32_16x16x32_bf16(a0[i][0], b1[j][0], acc[i][j + 2], 0, 0, 0); \
        acc[i][j + 2] = __builtin_amdgcn_mfma_f32_16x16x32_bf16(a0[i][1], b1[j][1], acc[i][j + 2], 0, 0, 0); \
      }                                                                      \
    __builtin_amdgcn_s_setprio(0); SCB(); BAR();                             \
  } while (0)

#define PH_C(P, STJ) do {                                                    \
    const int ab__ = (P) * 32768;                                            \
    _Pragma("unroll") for (int i = 0; i < 4; i++)                            \
      _Pragma("unroll") for (int s = 0; s < 2; s++)                          \
        a1[i][s] = *(const bf16x8_t*)&lds[ab__ + (128 + wm * 64 + i * 16 + l15) * 64 + (((s * 4 + lg) ^ swl) << 3)]; \
    if ((STJ) >= 0) STAGE(STJ);                                              \
    SCB(); BAR(); LGKM0(); SCB();                                            \
    __builtin_amdgcn_s_setprio(1);                                           \
    _Pragma("unroll") for (int i = 0; i < 4; i++)                            \
      _Pragma("unroll") for (int j = 0; j < 2; j++) {                        \
        acc[i + 4][j + 2] = __builtin_amdgcn_mfma_f32_16x16x32_bf16(a1[i][0], b1[j][0], acc[i + 4][j + 2], 0, 0, 0); \
        acc[i + 4][j + 2] = __builtin_amdgcn_mfma_f32_16x16x32_bf16(a1[i][1], b1[j][1], acc[i + 4][j + 2], 0, 0, 0); \
      }                                                                      \
    __builtin_amdgcn_s_setprio(0); SCB(); BAR();                             \
  } while (0)

#define PH_D(P, STJ, VM) do {                                                \
    if ((STJ) >= 0) STAGE(STJ);                                              \
    SCB(); BAR();                                                            \
    __builtin_amdgcn_s_setprio(1);                                           \
    _Pragma("unroll") for (int i = 0; i < 4; i++)                            \
      _Pragma("unroll") for (int j = 0; j < 2; j++) {                        \
        acc[i + 4][j] = __builtin_amdgcn_mfma_f32_16x16x32_bf16(a1[i][0], b0[j][0], acc[i + 4][j], 0, 0, 0); \
        acc[i + 4][j] = __builtin_amdgcn_mfma_f32_16x16x32_bf16(a1[i][1], b0[j][1], acc[i + 4][j], 0, 0, 0); \
      }                                                                      \
    __builtin_amdgcn_s_setprio(0);                                           \
    if ((VM) == 6) asm volatile("s_waitcnt vmcnt(6)" ::: "memory");          \
    else if ((VM) == 0) asm volatile("s_waitcnt vmcnt(0)" ::: "memory");     \
    SCB(); BAR();                                                            \
  } while (0)

  STAGE(0); STAGE(1); STAGE(2); STAGE(3); STAGE(4); STAGE(5); STAGE(6);
  asm volatile("s_waitcnt vmcnt(6)" ::: "memory");  // tile0 landed
  SCB(); BAR();

#pragma unroll 1
  for (int tp = 0; tp < 3; ++tp) {
    const int g0 = tp * 8;
    PH_A(0, g0 + 7);  PH_B(0, g0 + 8);  PH_C(0, g0 + 9);  PH_D(0, g0 + 10, 6);
    PH_A(1, g0 + 11); PH_B(1, g0 + 12); PH_C(1, g0 + 13); PH_D(1, g0 + 14, 6);
  }
  PH_A(0, 31); PH_B(0, -1); PH_C(0, -1); PH_D(0, -1, 0);
  PH_A(1, -1); PH_B(1, -1); PH_C(1, -1); PH_D(1, -1, -1);

#undef PH_A
#undef PH_B
#undef PH_C
#undef PH_D
#undef STAGE

  // epilogue: C/D layout col=lane&15, row=(lane>>4)*4+reg  [m89-verified]
#pragma unroll
  for (int i = 0; i < 8; i++) {
#pragma unroll
    for (int rr = 0; rr < 4; rr++) {
      const int m = m0 + (i >> 2) * 128 + wm * 64 + (i & 3) * 16 + lg * 4 + rr;
      if (MODE == 0) {
        __bf16* outz = (__bf16*)outp + (size_t)bz * ((size_t)BT_ * D_);
        const int bb = m >> 8, tt = m & 255;
        const size_t rbase = ((size_t)bb * H_) * T_ * HD_ + (size_t)tt * HD_;
#pragma unroll
        for (int j = 0; j < 4; j++) {
          const int c = n0 + (j >> 1) * 128 + wn * 32 + (j & 1) * 16 + l15;
          const int hh = c >> 6, dd = c & 63;
          outz[rbase + (size_t)hh * (T_ * HD_) + dd] = (__bf16)acc[i][j][rr];
        }
      } else {
        float* outf = (float*)outp;
#pragma unroll
        for (int j = 0; j < 4; j++) {
          const int c = n0 + (j >> 1) * 128 + wn * 32 + (j & 1) * 16 + l15;
          outf[(size_t)m * D_ + c] = acc[i][j][rr];
        }
      }
    }
  }
}

// ---------------- attention v3: fused RMSNorm+RoPE on Q and K ----------------
// One block per (b,h), 8 balanced waves, fixed-shift softmax (shift=50),
// 80KB LDS -> 2 blocks/CU, chunked PV (round-7 verified structure).
// K: normed/roped in registers during staging (8-lane shfl row-sum, shfl_xor(4)
// rotate-half partner). Q: normed/roped at fragment load (shfl_xor{16,32}
// row-sum; rotate-half pairs are aq0[j]<->aq1[j] in-lane). Same math/tables as
// the old norm_rope kernel -> numerics unchanged modulo summation order.
__global__ __launch_bounds__(512, 2) void attn_kernel(
    const __bf16* __restrict__ qb, const __bf16* __restrict__ kb,
    const __bf16* __restrict__ vb, __bf16* __restrict__ ob,
    const float* __restrict__ gq, const float* __restrict__ gk,
    const float* __restrict__ rc, const float* __restrict__ rs) {
  __shared__ __bf16 Kl[256 * 64];   // 32 KB
  __shared__ __bf16 VT[64 * 256];   // 32 KB (V transposed, d-major)
  __shared__ __bf16 Pl[8 * 16 * 64];// 16 KB (per-wave 64-key chunk)
  const int bh = blockIdx.x;
  const __bf16* Qg = qb + (size_t)bh * (T_ * HD_);
  const __bf16* Kg = kb + (size_t)bh * (T_ * HD_);
  const __bf16* Vg = vb + (size_t)bh * (T_ * HD_);
  const int tid = threadIdx.x, lane = tid & 63, w = tid >> 6;
  const int bI = bh >> 3, hI = bh & 7;

#pragma unroll
  for (int p = 0; p < 4; p++) {
    const int t = p * 64 + (tid >> 3);
    const int a = tid & 7;
    const int d0 = a * 8;
    // ---- K: load -> f32 -> RMSNorm -> RoPE -> bf16 -> swizzled LDS store ----
    bf16x8_t kv = *(const bf16x8_t*)&Kg[t * HD_ + d0];
    float kf[8], ss = 0.f;
#pragma unroll
    for (int j = 0; j < 8; j++) { kf[j] = (float)kv[j]; ss += kf[j] * kf[j]; }
    ss += __shfl_xor(ss, 1); ss += __shfl_xor(ss, 2); ss += __shfl_xor(ss, 4);
    const float rn = rsqrtf(ss * 0.015625f + 1e-6f);
    const f32x4_t gk0 = *(const f32x4_t*)&gk[d0];
    const f32x4_t gk1 = *(const f32x4_t*)&gk[d0 + 4];
    float vn[8];
#pragma unroll
    for (int j = 0; j < 8; j++) vn[j] = kf[j] * rn * ((j < 4) ? gk0[j] : gk1[j - 4]);
    float pn[8];
#pragma unroll
    for (int j = 0; j < 8; j++) pn[j] = __shfl_xor(vn[j], 4);  // rotate-half partner
    const int f0 = (a & 3) * 8;                                // freq base (d % 32)
    const f32x4_t c0 = *(const f32x4_t*)&rc[t * 32 + f0];
    const f32x4_t c1 = *(const f32x4_t*)&rc[t * 32 + f0 + 4];
    const f32x4_t s0 = *(const f32x4_t*)&rs[t * 32 + f0];
    const f32x4_t s1 = *(const f32x4_t*)&rs[t * 32 + f0 + 4];
    const float sg = (a < 4) ? -1.f : 1.f;
    bf16x8_t ko;
#pragma unroll
    for (int j = 0; j < 8; j++) {
      const float cc = (j < 4) ? c0[j] : c1[j - 4];
      const float sS = (j < 4) ? s0[j] : s1[j - 4];
      ko[j] = (__bf16)(vn[j] * cc + sg * pn[j] * sS);
    }
    *(bf16x8_t*)&Kl[t * 64 + (((a ^ (t & 7)) << 3))] = ko;
    // ---- V: plain transpose staging (unchanged) ----
    bf16x8_t vv = *(const bf16x8_t*)&Vg[t * HD_ + d0];
#pragma unroll
    for (int j = 0; j < 8; j++) {
      const int row = d0 + j;                       // V d-dim
      const int rk = (row & 7) ^ ((row >> 3) & 7);
      VT[row * 256 + (((t >> 3) ^ rk) << 3) + (t & 7)] = vv[j];
    }
  }
  __syncthreads();

  const int l15 = lane & 15;
  const int lg = lane >> 4;
  const int sw = l15 & 7;
  const f32x4_t zero = {0.f, 0.f, 0.f, 0.f};
  const float C1 = 0.0072134752f;      // 0.125 * 0.04 * log2(e)
  const float LOG2E = 1.44269504f;

  for (int half = 0; half < 2; half++) {
    const int qt = half ? (15 - w) : w;   // balanced: every wave ~18 even-tiles
    const int q0 = qt * 16;
    const int tq = q0 + l15;              // this lane's q-row (token index)
    // ---- Q: load -> f32 -> RMSNorm -> RoPE -> bf16 fragments ----
    bf16x8_t q0r = *(const bf16x8_t*)&Qg[tq * HD_ + lg * 8];
    bf16x8_t q1r = *(const bf16x8_t*)&Qg[tq * HD_ + 32 + lg * 8];
    float qf0[8], qf1[8], qss = 0.f;
#pragma unroll
    for (int j = 0; j < 8; j++) {
      qf0[j] = (float)q0r[j]; qf1[j] = (float)q1r[j];
      qss += qf0[j] * qf0[j] + qf1[j] * qf1[j];
    }
    qss += __shfl_xor(qss, 16); qss += __shfl_xor(qss, 32);
    const float qrn = rsqrtf(qss * 0.015625f + 1e-6f);
    const f32x4_t gqa = *(const f32x4_t*)&gq[lg * 8];
    const f32x4_t gqb2 = *(const f32x4_t*)&gq[lg * 8 + 4];
    const f32x4_t gqc = *(const f32x4_t*)&gq[32 + lg * 8];
    const f32x4_t gqd = *(const f32x4_t*)&gq[32 + lg * 8 + 4];
    const f32x4_t qc0 = *(const f32x4_t*)&rc[tq * 32 + lg * 8];
    const f32x4_t qc1 = *(const f32x4_t*)&rc[tq * 32 + lg * 8 + 4];
    const f32x4_t qs0 = *(const f32x4_t*)&rs[tq * 32 + lg * 8];
    const f32x4_t qs1 = *(const f32x4_t*)&rs[tq * 32 + lg * 8 + 4];
    bf16x8_t aq0, aq1;
#pragma unroll
    for (int j = 0; j < 8; j++) {
      const float glo = (j < 4) ? gqa[j] : gqb2[j - 4];
      const float ghi = (j < 4) ? gqc[j] : gqd[j - 4];
      const float cc  = (j < 4) ? qc0[j] : qc1[j - 4];
      const float sS  = (j < 4) ? qs0[j] : qs1[j - 4];
      const float vlo = qf0[j] * qrn * glo;
      const float vhi = qf1[j] * qrn * ghi;
      aq0[j] = (__bf16)(vlo * cc - vhi * sS);
      aq1[j] = (__bf16)(vhi * cc + vlo * sS);
    }

    const int ntiles_e = (qt + 2) & ~1;
    const int qr = q0 + (lg << 2);

    f32x4_t ls = {0.f, 0.f, 0.f, 0.f};
    f32x4_t o[4];
#pragma unroll
    for (int j = 0; j < 4; j++) o[j] = zero;

    for (int t0 = 0; t0 < ntiles_e; t0 += 4) {     // 64-key chunks
      const int te = (t0 + 4 < ntiles_e) ? (t0 + 4) : ntiles_e;
      for (int n = t0; n < te; ++n) {
        bf16x8_t kb0 = *(const bf16x8_t*)&Kl[(n * 16 + l15) * 64 + ((lg ^ sw) << 3)];
        bf16x8_t kb1 = *(const bf16x8_t*)&Kl[(n * 16 + l15) * 64 + (((4 + lg) ^ sw) << 3)];
        f32x4_t a = __builtin_amdgcn_mfma_f32_16x16x32_bf16(aq0, kb0, zero, 0, 0, 0);
        a = __builtin_amdgcn_mfma_f32_16x16x32_bf16(aq1, kb1, a, 0, 0, 0);
        const int key = n * 16 + l15;
        const int lsl = ((n - t0) << 1) + (l15 >> 3);   // chunk-local slot
#pragma unroll
        for (int r = 0; r < 4; r++) {
          float e2 = __builtin_amdgcn_exp2f(a[r] * C1);
          float cm = -100.f * __builtin_amdgcn_rcpf(e2 + 1.f);  // cap - 50
          float p = __builtin_amdgcn_exp2f(cm * LOG2E);
          p = (key <= qr + r) ? p : 0.f;
          ls[r] += p;
          const int ro = (lg << 2) + r;
          Pl[w * 1024 + ro * 64 + ((lsl ^ (ro & 7)) << 3) + (l15 & 7)] = (__bf16)p;
        }
      }
      asm volatile("s_waitcnt lgkmcnt(0)" ::: "memory");
      __builtin_amdgcn_sched_barrier(0);
      const int nkc = (te - t0) >> 1;
      for (int kcc = 0; kcc < nkc; ++kcc) {
        bf16x8_t pa = *(const bf16x8_t*)&Pl[w * 1024 + l15 * 64 + (((kcc * 4 + lg) ^ sw) << 3)];
#pragma unroll
        for (int j = 0; j < 4; j++) {
          const int row = j * 16 + l15;
          const int rk = sw ^ ((2 * j + (l15 >> 3)) & 7);   // VT key for this row
          const int sl = (t0 << 1) + kcc * 4 + lg;          // global 16B slot
          bf16x8_t bv = *(const bf16x8_t*)&VT[row * 256 + ((sl ^ rk) << 3)];
          o[j] = __builtin_amdgcn_mfma_f32_16x16x32_bf16(pa, bv, o[j], 0, 0, 0);
        }
      }
    }

#pragma unroll
    for (int off = 1; off < 16; off <<= 1) {
#pragma unroll
      for (int r = 0; r < 4; r++) ls[r] += __shfl_xor(ls[r], off);
    }

    float rl[4];
#pragma unroll
    for (int r = 0; r < 4; r++) rl[r] = 1.0f / ls[r];
#pragma unroll
    for (int j = 0; j < 4; j++) {
      int dd = j * 16 + l15;
#pragma unroll
      for (int r = 0; r < 4; r++) {
        int q = qr + r;
        ob[((size_t)(bI * T_ + q)) * D_ + hI * HD_ + dd] = (__bf16)(o[j][r] * rl[r]);
      }
    }
  }
}

// ---------------- launch ----------------
extern "C" void kernel_launch(void* const* d_in, const int* in_sizes, int n_in,
                              void* d_out, int out_size, void* d_ws, size_t ws_size,
                              hipStream_t stream) {
  (void)in_sizes; (void)n_in; (void)out_size; (void)ws_size;
  const float* x  = (const float*)d_in[0];
  const float* wq = (const float*)d_in[1];
  const float* wk = (const float*)d_in[2];
  const float* wv = (const float*)d_in[3];
  const float* wo = (const float*)d_in[4];
  const float* gq = (const float*)d_in[5];
  const float* gk = (const float*)d_in[6];

  // ws layout (bytes): xb 64MB (aliased by attn-out) | q 64MB | k 64MB | v 64MB | w 2MB | rope 64KB
  char* ws = (char*)d_ws;
  __bf16* xb   = (__bf16*)ws;
  __bf16* qkvb = (__bf16*)(ws + 67108864UL);
  __bf16* qb = qkvb;
  __bf16* kb = qkvb + 33554432UL;
  __bf16* vb = qkvb + 67108864UL;
  __bf16* wb = (__bf16*)(ws + 4UL * 67108864UL);
  float*  rc = (float*)(ws + 4UL * 67108864UL + 2097152UL);
  float*  rs = rc + 8192;
  __bf16* ob = xb;  // alias: xb dead after QKV GEMM

  prep<<<dim3(2336), 256, 0, stream>>>(x, wq, wk, wv, wo, xb, wb, rc, rs);
  gemm256<0><<<dim3(1536), 512, 0, stream>>>(xb, wb, (void*)qkvb);
  attn_kernel<<<dim3(2048), 512, 0, stream>>>(qb, kb, vb, ob, gq, gk, rc, rs);
  gemm256<1><<<dim3(512), 512, 0, stream>>>(ob, wb + 3UL * 262144UL, d_out);
}

// Round 10
// 303.502 us; speedup vs baseline: 1.3968x; 1.0008x over previous
//
#include <hip/hip_runtime.h>
#include <cstdint>
#include <cstddef>

// Problem constants (reference: B=256, T=256, D=512, H=8, hd=64)
#define B_   256
#define T_   256
#define D_   512
#define H_   8
#define HD_  64
#define BT_  65536
#define KDIM 512

typedef __bf16 bf16x8_t __attribute__((ext_vector_type(8)));
typedef __bf16 bf16x4_t __attribute__((ext_vector_type(4)));
typedef float  f32x4_t  __attribute__((ext_vector_type(4)));

__device__ __forceinline__ void gload16(const void* gp, void* lp) {
  // async global->LDS, 16B per lane; LDS dest = wave-uniform base + lane*16
  __builtin_amdgcn_global_load_lds(
      (const __attribute__((address_space(1))) void*)gp,
      (__attribute__((address_space(3))) void*)lp, 16, 0, 0);
}

#define BAR()   __builtin_amdgcn_s_barrier()
#define SCB()   __builtin_amdgcn_sched_barrier(0)
#define LGKM0() asm volatile("s_waitcnt lgkmcnt(0)" ::: "memory")

// ---------------- fused prep: cast x, cast weights, rope tables ----------------
__global__ __launch_bounds__(256) void prep(
    const float* __restrict__ x,
    const float* __restrict__ wq, const float* __restrict__ wk,
    const float* __restrict__ wv, const float* __restrict__ wo,
    __bf16* __restrict__ xb, __bf16* __restrict__ wb,
    float* __restrict__ rc, float* __restrict__ rs) {
  const int b = blockIdx.x;
  if (b < 2048) {
    for (size_t i = (size_t)b * 256 + threadIdx.x; i < 8388608UL; i += 524288UL) {
      f32x4_t v = *(const f32x4_t*)&x[i * 4];
      bf16x4_t o;
      o[0] = (__bf16)v[0]; o[1] = (__bf16)v[1]; o[2] = (__bf16)v[2]; o[3] = (__bf16)v[3];
      *(bf16x4_t*)&xb[i * 4] = o;
    }
  } else if (b < 2304) {
    for (int i = (b - 2048) * 256 + threadIdx.x; i < 262144; i += 65536) {
      int which = i >> 16;
      int off   = (i & 65535) * 4;
      const float* src = (which == 0) ? wq : (which == 1) ? wk : (which == 2) ? wv : wo;
      f32x4_t v = *(const f32x4_t*)&src[off];
      bf16x4_t o;
      o[0] = (__bf16)v[0]; o[1] = (__bf16)v[1]; o[2] = (__bf16)v[2]; o[3] = (__bf16)v[3];
      *(bf16x4_t*)&wb[(size_t)which * 262144 + off] = o;
    }
  } else {
    int idx = (b - 2304) * 256 + threadIdx.x;
    if (idx < T_ * 32) {
      int t = idx >> 5, j = idx & 31;
      float inv = powf(10000.f, -(float)j * (1.0f / 32.0f));  // 10000^(-2j/64)
      float a = (float)t * inv;
      rc[idx] = cosf(a);
      rs[idx] = sinf(a);
    }
  }
}

// ---------------- 256x256 GEMM, BK=64, 8 waves, 8-phase schedule, T2 swizzle --
// (round-9 verified: conflicts 0, FETCH 86MB via z/N-fastest decode)
// MODE 0: 3 z-passes (Q,K,V), bf16 scatter to (B,H,T,hd), grid 1536.
// MODE 1: single pass, f32 row-major (m,512), grid 512.
template <int MODE>
__global__ __launch_bounds__(512, 2) void gemm256(
    const __bf16* __restrict__ A, const __bf16* __restrict__ W,
    void* __restrict__ outp) {
  __shared__ __bf16 lds[65536];  // [dbuf2][mat2][256][64] bf16 = 128 KiB
  const int tid = threadIdx.x;
  const int lane = tid & 63, w = tid >> 6;
  const int wm = w >> 2, wn = w & 3;          // 2 x 4 waves
  const int l15 = lane & 15, lg = lane >> 4;
  const int swl = l15 & 7;                    // read-side swizzle key (== row&7)

  // XCD-aware swizzle (grid % 8 == 0; 1536 or 512)
  const int cpx = gridDim.x >> 3;
  const int swz = (blockIdx.x & 7) * cpx + (blockIdx.x >> 3);
  // z/N fastest: consecutive swz (same XCD chunk) share the A-panel
  int m_idx, bz, bx;
  if (MODE == 0) {
    m_idx = swz / 6;
    const int rem = swz - m_idx * 6;
    bz = rem >> 1;
    bx = rem & 1;
  } else {
    m_idx = swz >> 1;
    bz = 0;
    bx = swz & 1;
  }
  const int m0 = m_idx * 256, n0 = bx * 256;

  const __bf16* Ag = A + (size_t)m0 * KDIM;
  const __bf16* Bg = W + (size_t)bz * (KDIM * KDIM) + (size_t)n0 * KDIM;
  const int srow = tid >> 3;          // 0..63
  // inverse swizzle on global source (gload_lds dest must stay linear)
  const int scol = (((tid & 7) ^ ((tid >> 3) & 7)) * 8);

#define STAGE(J) do {                                                        \
    const int T__ = (J) >> 2, r__ = (J) & 3;                                 \
    const int h__ = r__ >> 1;                                                \
    const int isB__ = (r__ == 1 || r__ == 2);                                \
    const size_t grow__ = (size_t)(h__ * 128 + srow) * KDIM + T__ * 64 + scol; \
    const __bf16* gp__ = isB__ ? (Bg + grow__) : (Ag + grow__);              \
    __bf16* lp__ = &lds[(T__ & 1) * 32768 + isB__ * 16384 + (h__ * 128 + w * 8) * 64]; \
    gload16(gp__, lp__);                                                     \
    gload16(gp__ + 64 * KDIM, lp__ + 64 * 64);                               \
  } while (0)

  f32x4_t acc[8][4];
#pragma unroll
  for (int i = 0; i < 8; i++)
#pragma unroll
    for (int j = 0; j < 4; j++) acc[i][j] = (f32x4_t){0.f, 0.f, 0.f, 0.f};

  bf16x8_t a0[4][2], a1[4][2], b0[2][2], b1[2][2];

#define PH_A(P, STJ) do {                                                    \
    const int ab__ = (P) * 32768;                                            \
    _Pragma("unroll") for (int i = 0; i < 4; i++)                            \
      _Pragma("unroll") for (int s = 0; s < 2; s++)                          \
        a0[i][s] = *(const bf16x8_t*)&lds[ab__ + (wm * 64 + i * 16 + l15) * 64 + (((s * 4 + lg) ^ swl) << 3)]; \
    _Pragma("unroll") for (int j = 0; j < 2; j++)                            \
      _Pragma("unroll") for (int s = 0; s < 2; s++)                          \
        b0[j][s] = *(const bf16x8_t*)&lds[ab__ + 16384 + (wn * 32 + j * 16 + l15) * 64 + (((s * 4 + lg) ^ swl) << 3)]; \
    if ((STJ) >= 0) STAGE(STJ);                                              \
    SCB(); BAR(); LGKM0(); SCB();                                            \
    __builtin_amdgcn_s_setprio(1);                                           \
    _Pragma("unroll") for (int i = 0; i < 4; i++)                            \
      _Pragma("unroll") for (int j = 0; j < 2; j++) {                        \
        acc[i][j] = __builtin_amdgcn_mfma_f32_16x16x32_bf16(a0[i][0], b0[j][0], acc[i][j], 0, 0, 0); \
        acc[i][j] = __builtin_amdgcn_mfma_f32_16x16x32_bf16(a0[i][1], b0[j][1], acc[i][j], 0, 0, 0); \
      }                                                                      \
    __builtin_amdgcn_s_setprio(0); SCB(); BAR();                             \
  } while (0)

#define PH_B(P, STJ) do {                                                    \
    const int ab__ = (P) * 32768;                                            \
    _Pragma("unroll") for (int j = 0; j < 2; j++)                            \
      _Pragma("unroll") for (int s = 0; s < 2; s++)                          \
        b1[j][s] = *(const bf16x8_t*)&lds[ab__ + 16384 + (128 + wn * 32 + j * 16 + l15) * 64 + (((s * 4 + lg) ^ swl) << 3)]; \
    if ((STJ) >= 0) STAGE(STJ);                                              \
    SCB(); BAR(); LGKM0(); SCB();                                            \
    __builtin_amdgcn_s_setprio(1);                                           \
    _Pragma("unroll") for (int i = 0; i < 4; i++)                            \
      _Pragma("unroll") for (int j = 0; j < 2; j++) {                        \
        acc[i][j + 2] = __builtin_amdgcn_mfma_f32_16x16x32_bf16(a0[i][0], b1[j][0], acc[i][j + 2], 0, 0, 0); \
        acc[i][j + 2] = __builtin_amdgcn_mfma_f32_16x16x32_bf16(a0[i][1], b1[j][1], acc[i][j + 2], 0, 0, 0); \
      }                                                                      \
    __builtin_amdgcn_s_setprio(0); SCB(); BAR();                             \
  } while (0)

#define PH_C(P, STJ) do {                                                    \
    const int ab__ = (P) * 32768;                                            \
    _Pragma("unroll") for (int i = 0; i < 4; i++)                            \
      _Pragma("unroll") for (int s = 0; s < 2; s++)                          \
        a1[i][s] = *(const bf16x8_t*)&lds[ab__ + (128 + wm * 64 + i * 16 + l15) * 64 + (((s * 4 + lg) ^ swl) << 3)]; \
    if ((STJ) >= 0) STAGE(STJ);                                              \
    SCB(); BAR(); LGKM0(); SCB();                                            \
    __builtin_amdgcn_s_setprio(1);                                           \
    _Pragma("unroll") for (int i = 0; i < 4; i++)                            \
      _Pragma("unroll") for (int j = 0; j < 2; j++) {                        \
        acc[i + 4][j + 2] = __builtin_amdgcn_mfma_f32_16x16x32_bf16(a1[i][0], b1[j][0], acc[i + 4][j + 2], 0, 0, 0); \
        acc[i + 4][j + 2] = __builtin_amdgcn_mfma_f32_16x16x32_bf16(a1[i][1], b1[j][1], acc[i + 4][j + 2], 0, 0, 0); \
      }                                                                      \
    __builtin_amdgcn_s_setprio(0); SCB(); BAR();                             \
  } while (0)

#define PH_D(P, STJ, VM) do {                                                \
    if ((STJ) >= 0) STAGE(STJ);                                              \
    SCB(); BAR();                                                            \
    __builtin_amdgcn_s_setprio(1);                                           \
    _Pragma("unroll") for (int i = 0; i < 4; i++)                            \
      _Pragma("unroll") for (int j = 0; j < 2; j++) {                        \
        acc[i + 4][j] = __builtin_amdgcn_mfma_f32_16x16x32_bf16(a1[i][0], b0[j][0], acc[i + 4][j], 0, 0, 0); \
        acc[i + 4][j] = __builtin_amdgcn_mfma_f32_16x16x32_bf16(a1[i][1], b0[j][1], acc[i + 4][j], 0, 0, 0); \
      }                                                                      \
    __builtin_amdgcn_s_setprio(0);                                           \
    if ((VM) == 6) asm volatile("s_waitcnt vmcnt(6)" ::: "memory");          \
    else if ((VM) == 0) asm volatile("s_waitcnt vmcnt(0)" ::: "memory");     \
    SCB(); BAR();                                                            \
  } while (0)

  STAGE(0); STAGE(1); STAGE(2); STAGE(3); STAGE(4); STAGE(5); STAGE(6);
  asm volatile("s_waitcnt vmcnt(6)" ::: "memory");  // tile0 landed
  SCB(); BAR();

#pragma unroll 1
  for (int tp = 0; tp < 3; ++tp) {
    const int g0 = tp * 8;
    PH_A(0, g0 + 7);  PH_B(0, g0 + 8);  PH_C(0, g0 + 9);  PH_D(0, g0 + 10, 6);
    PH_A(1, g0 + 11); PH_B(1, g0 + 12); PH_C(1, g0 + 13); PH_D(1, g0 + 14, 6);
  }
  PH_A(0, 31); PH_B(0, -1); PH_C(0, -1); PH_D(0, -1, 0);
  PH_A(1, -1); PH_B(1, -1); PH_C(1, -1); PH_D(1, -1, -1);

#undef PH_A
#undef PH_B
#undef PH_C
#undef PH_D
#undef STAGE

  // epilogue: C/D layout col=lane&15, row=(lane>>4)*4+reg  [m89-verified]
#pragma unroll
  for (int i = 0; i < 8; i++) {
#pragma unroll
    for (int rr = 0; rr < 4; rr++) {
      const int m = m0 + (i >> 2) * 128 + wm * 64 + (i & 3) * 16 + lg * 4 + rr;
      if (MODE == 0) {
        __bf16* outz = (__bf16*)outp + (size_t)bz * ((size_t)BT_ * D_);
        const int bb = m >> 8, tt = m & 255;
        const size_t rbase = ((size_t)bb * H_) * T_ * HD_ + (size_t)tt * HD_;
#pragma unroll
        for (int j = 0; j < 4; j++) {
          const int c = n0 + (j >> 1) * 128 + wn * 32 + (j & 1) * 16 + l15;
          const int hh = c >> 6, dd = c & 63;
          outz[rbase + (size_t)hh * (T_ * HD_) + dd] = (__bf16)acc[i][j][rr];
        }
      } else {
        float* outf = (float*)outp;
#pragma unroll
        for (int j = 0; j < 4; j++) {
          const int c = n0 + (j >> 1) * 128 + wn * 32 + (j & 1) * 16 + l15;
          outf[(size_t)m * D_ + c] = acc[i][j][rr];
        }
      }
    }
  }
}

// ---------------- attention v4: swapped QK^T, wide P stores, fused norm+rope --
// One block per (b,h), 8 balanced waves, fixed-shift softmax (shift=50),
// 80KB LDS -> 2 blocks/CU, chunked PV (round-7/9 verified shell).
// v4: compute mfma(K,Q) = S^T: C col=l15 -> q (lane-uniform), row=4lg+r -> key.
//  - lane's 4 P values = 4 CONSECUTIVE keys of one q-row -> ONE ds_write_b64
//    per tile (was 4 scattered u16). Pl row = 128B; 16B-slot XOR swizzle
//    (^(l15&7)): b64 writes 2-way (free), b128 reads = one 16B slot, no
//    straddle, conflict-free.
//  - ls is lane-local scalar (all 4 share q=l15): reduce = 2 shfl_xor; 1/ls
//    redistributed to output rows via 4 shfl.
//  - Q is the B-operand (col=l15) -> Q load/norm/rope path unchanged; K is the
//    A-operand with identical lane mapping -> Kl reads unchanged; PV + output
//    addressing unchanged (q = q0+4lg+r as before).
// T5: setprio(1) around MFMA clusters (m191: +4-7% attn).
__global__ __launch_bounds__(512, 2) void attn_kernel(
    const __bf16* __restrict__ qb, const __bf16* __restrict__ kb,
    const __bf16* __restrict__ vb, __bf16* __restrict__ ob,
    const float* __restrict__ gq, const float* __restrict__ gk,
    const float* __restrict__ rc, const float* __restrict__ rs) {
  __shared__ __bf16 Kl[256 * 64];   // 32 KB
  __shared__ __bf16 VT[64 * 256];   // 32 KB (V transposed, d-major)
  __shared__ __bf16 Pl[8 * 16 * 64];// 16 KB (per-wave 64-key chunk, q-major)
  const int bh = blockIdx.x;
  const __bf16* Qg = qb + (size_t)bh * (T_ * HD_);
  const __bf16* Kg = kb + (size_t)bh * (T_ * HD_);
  const __bf16* Vg = vb + (size_t)bh * (T_ * HD_);
  const int tid = threadIdx.x, lane = tid & 63, w = tid >> 6;
  const int bI = bh >> 3, hI = bh & 7;

#pragma unroll
  for (int p = 0; p < 4; p++) {
    const int t = p * 64 + (tid >> 3);
    const int a = tid & 7;
    const int d0 = a * 8;
    // ---- K: load -> f32 -> RMSNorm -> RoPE -> bf16 -> swizzled LDS store ----
    bf16x8_t kv = *(const bf16x8_t*)&Kg[t * HD_ + d0];
    float kf[8], ss = 0.f;
#pragma unroll
    for (int j = 0; j < 8; j++) { kf[j] = (float)kv[j]; ss += kf[j] * kf[j]; }
    ss += __shfl_xor(ss, 1); ss += __shfl_xor(ss, 2); ss += __shfl_xor(ss, 4);
    const float rn = rsqrtf(ss * 0.015625f + 1e-6f);
    const f32x4_t gk0 = *(const f32x4_t*)&gk[d0];
    const f32x4_t gk1 = *(const f32x4_t*)&gk[d0 + 4];
    float vn[8];
#pragma unroll
    for (int j = 0; j < 8; j++) vn[j] = kf[j] * rn * ((j < 4) ? gk0[j] : gk1[j - 4]);
    float pn[8];
#pragma unroll
    for (int j = 0; j < 8; j++) pn[j] = __shfl_xor(vn[j], 4);  // rotate-half partner
    const int f0 = (a & 3) * 8;                                // freq base (d % 32)
    const f32x4_t c0 = *(const f32x4_t*)&rc[t * 32 + f0];
    const f32x4_t c1 = *(const f32x4_t*)&rc[t * 32 + f0 + 4];
    const f32x4_t s0 = *(const f32x4_t*)&rs[t * 32 + f0];
    const f32x4_t s1 = *(const f32x4_t*)&rs[t * 32 + f0 + 4];
    const float sg = (a < 4) ? -1.f : 1.f;
    bf16x8_t ko;
#pragma unroll
    for (int j = 0; j < 8; j++) {
      const float cc = (j < 4) ? c0[j] : c1[j - 4];
      const float sS = (j < 4) ? s0[j] : s1[j - 4];
      ko[j] = (__bf16)(vn[j] * cc + sg * pn[j] * sS);
    }
    *(bf16x8_t*)&Kl[t * 64 + (((a ^ (t & 7)) << 3))] = ko;
    // ---- V: plain transpose staging (unchanged) ----
    bf16x8_t vv = *(const bf16x8_t*)&Vg[t * HD_ + d0];
#pragma unroll
    for (int j = 0; j < 8; j++) {
      const int row = d0 + j;                       // V d-dim
      const int rk = (row & 7) ^ ((row >> 3) & 7);
      VT[row * 256 + (((t >> 3) ^ rk) << 3) + (t & 7)] = vv[j];
    }
  }
  __syncthreads();

  const int l15 = lane & 15;
  const int lg = lane >> 4;
  const int sw = l15 & 7;
  const f32x4_t zero = {0.f, 0.f, 0.f, 0.f};
  const float C1 = 0.0072134752f;      // 0.125 * 0.04 * log2(e)
  const float LOG2E = 1.44269504f;

  for (int half = 0; half < 2; half++) {
    const int qt = half ? (15 - w) : w;   // balanced: every wave ~18 even-tiles
    const int q0 = qt * 16;
    const int tq = q0 + l15;              // this lane's q-row (token index)
    // ---- Q: load -> f32 -> RMSNorm -> RoPE -> bf16 fragments (B-operand) ----
    bf16x8_t q0r = *(const bf16x8_t*)&Qg[tq * HD_ + lg * 8];
    bf16x8_t q1r = *(const bf16x8_t*)&Qg[tq * HD_ + 32 + lg * 8];
    float qf0[8], qf1[8], qss = 0.f;
#pragma unroll
    for (int j = 0; j < 8; j++) {
      qf0[j] = (float)q0r[j]; qf1[j] = (float)q1r[j];
      qss += qf0[j] * qf0[j] + qf1[j] * qf1[j];
    }
    qss += __shfl_xor(qss, 16); qss += __shfl_xor(qss, 32);
    const float qrn = rsqrtf(qss * 0.015625f + 1e-6f);
    const f32x4_t gqa = *(const f32x4_t*)&gq[lg * 8];
    const f32x4_t gqb2 = *(const f32x4_t*)&gq[lg * 8 + 4];
    const f32x4_t gqc = *(const f32x4_t*)&gq[32 + lg * 8];
    const f32x4_t gqd = *(const f32x4_t*)&gq[32 + lg * 8 + 4];
    const f32x4_t qc0 = *(const f32x4_t*)&rc[tq * 32 + lg * 8];
    const f32x4_t qc1 = *(const f32x4_t*)&rc[tq * 32 + lg * 8 + 4];
    const f32x4_t qs0 = *(const f32x4_t*)&rs[tq * 32 + lg * 8];
    const f32x4_t qs1 = *(const f32x4_t*)&rs[tq * 32 + lg * 8 + 4];
    bf16x8_t aq0, aq1;
#pragma unroll
    for (int j = 0; j < 8; j++) {
      const float glo = (j < 4) ? gqa[j] : gqb2[j - 4];
      const float ghi = (j < 4) ? gqc[j] : gqd[j - 4];
      const float cc  = (j < 4) ? qc0[j] : qc1[j - 4];
      const float sS  = (j < 4) ? qs0[j] : qs1[j - 4];
      const float vlo = qf0[j] * qrn * glo;
      const float vhi = qf1[j] * qrn * ghi;
      aq0[j] = (__bf16)(vlo * cc - vhi * sS);
      aq1[j] = (__bf16)(vhi * cc + vlo * sS);
    }

    const int ntiles_e = (qt + 2) & ~1;
    const int qr = q0 + (lg << 2);

    float ls = 0.f;
    f32x4_t o[4];
#pragma unroll
    for (int j = 0; j < 4; j++) o[j] = zero;

    for (int t0 = 0; t0 < ntiles_e; t0 += 4) {     // 64-key chunks
      const int te = (t0 + 4 < ntiles_e) ? (t0 + 4) : ntiles_e;
      for (int n = t0; n < te; ++n) {
        bf16x8_t kb0 = *(const bf16x8_t*)&Kl[(n * 16 + l15) * 64 + ((lg ^ sw) << 3)];
        bf16x8_t kb1 = *(const bf16x8_t*)&Kl[(n * 16 + l15) * 64 + (((4 + lg) ^ sw) << 3)];
        __builtin_amdgcn_s_setprio(1);
        f32x4_t a = __builtin_amdgcn_mfma_f32_16x16x32_bf16(kb0, aq0, zero, 0, 0, 0);
        a = __builtin_amdgcn_mfma_f32_16x16x32_bf16(kb1, aq1, a, 0, 0, 0);
        __builtin_amdgcn_s_setprio(0);
        const int kbase = n * 16 + (lg << 2);          // this lane's 4 keys
        bf16x4_t pk;
#pragma unroll
        for (int r = 0; r < 4; r++) {
          float e2 = __builtin_amdgcn_exp2f(a[r] * C1);
          float cm = -100.f * __builtin_amdgcn_rcpf(e2 + 1.f);  // cap - 50
          float p = __builtin_amdgcn_exp2f(cm * LOG2E);
          p = (kbase + r <= tq) ? p : 0.f;
          ls += p;
          pk[r] = (__bf16)p;
        }
        // one b64 store: row q=l15, logical 16B slot s16=2*nn+(lg>>1), half lg&1
        const int nn = n - t0;
        const int ph = (2 * nn + (lg >> 1)) ^ sw;
        *(bf16x4_t*)&Pl[w * 1024 + l15 * 64 + ph * 8 + (lg & 1) * 4] = pk;
      }
      asm volatile("s_waitcnt lgkmcnt(0)" ::: "memory");
      __builtin_amdgcn_sched_barrier(0);
      const int nkc = (te - t0) >> 1;
      for (int kcc = 0; kcc < nkc; ++kcc) {
        const int phr = (kcc * 4 + lg) ^ sw;           // read: one 16B slot
        bf16x8_t pa = *(const bf16x8_t*)&Pl[w * 1024 + l15 * 64 + phr * 8];
        __builtin_amdgcn_s_setprio(1);
#pragma unroll
        for (int j = 0; j < 4; j++) {
          const int row = j * 16 + l15;
          const int rk = sw ^ ((2 * j + (l15 >> 3)) & 7);   // VT key for this row
          const int sl = (t0 << 1) + kcc * 4 + lg;          // global 16B slot
          bf16x8_t bv = *(const bf16x8_t*)&VT[row * 256 + ((sl ^ rk) << 3)];
          o[j] = __builtin_amdgcn_mfma_f32_16x16x32_bf16(pa, bv, o[j], 0, 0, 0);
        }
        __builtin_amdgcn_s_setprio(0);
      }
    }

    // row-sum for q=l15: reduce over the 4 lane-groups
    ls += __shfl_xor(ls, 16);
    ls += __shfl_xor(ls, 32);
    const float inv = 1.0f / ls;
    float rl[4];
#pragma unroll
    for (int r = 0; r < 4; r++) rl[r] = __shfl(inv, (lg << 2) + r);

#pragma unroll
    for (int j = 0; j < 4; j++) {
      int dd = j * 16 + l15;
#pragma unroll
      for (int r = 0; r < 4; r++) {
        int q = qr + r;
        ob[((size_t)(bI * T_ + q)) * D_ + hI * HD_ + dd] = (__bf16)(o[j][r] * rl[r]);
      }
    }
  }
}

// ---------------- launch ----------------
extern "C" void kernel_launch(void* const* d_in, const int* in_sizes, int n_in,
                              void* d_out, int out_size, void* d_ws, size_t ws_size,
                              hipStream_t stream) {
  (void)in_sizes; (void)n_in; (void)out_size; (void)ws_size;
  const float* x  = (const float*)d_in[0];
  const float* wq = (const float*)d_in[1];
  const float* wk = (const float*)d_in[2];
  const float* wv = (const float*)d_in[3];
  const float* wo = (const float*)d_in[4];
  const float* gq = (const float*)d_in[5];
  const float* gk = (const float*)d_in[6];

  // ws layout (bytes): xb 64MB (aliased by attn-out) | q 64MB | k 64MB | v 64MB | w 2MB | rope 64KB
  char* ws = (char*)d_ws;
  __bf16* xb   = (__bf16*)ws;
  __bf16* qkvb = (__bf16*)(ws + 67108864UL);
  __bf16* qb = qkvb;
  __bf16* kb = qkvb + 33554432UL;
  __bf16* vb = qkvb + 67108864UL;
  __bf16* wb = (__bf16*)(ws + 4UL * 67108864UL);
  float*  rc = (float*)(ws + 4UL * 67108864UL + 2097152UL);
  float*  rs = rc + 8192;
  __bf16* ob = xb;  // alias: xb dead after QKV GEMM

  prep<<<dim3(2336), 256, 0, stream>>>(x, wq, wk, wv, wo, xb, wb, rc, rs);
  gemm256<0><<<dim3(1536), 512, 0, stream>>>(xb, wb, (void*)qkvb);
  attn_kernel<<<dim3(2048), 512, 0, stream>>>(qb, kb, vb, ob, gq, gk, rc, rs);
  gemm256<1><<<dim3(512), 512, 0, stream>>>(ob, wb + 3UL * 262144UL, d_out);
}

// Round 11
// 290.146 us; speedup vs baseline: 1.4611x; 1.0460x over previous
//
#include <hip/hip_runtime.h>
#include <cstdint>
#include <cstddef>

// Problem constants (reference: B=256, T=256, D=512, H=8, hd=64)
#define B_   256
#define T_   256
#define D_   512
#define H_   8
#define HD_  64
#define BT_  65536
#define KDIM 512

typedef __bf16 bf16x8_t __attribute__((ext_vector_type(8)));
typedef __bf16 bf16x4_t __attribute__((ext_vector_type(4)));
typedef float  f32x4_t  __attribute__((ext_vector_type(4)));

__device__ __forceinline__ void gload16(const void* gp, void* lp) {
  // async global->LDS, 16B per lane; LDS dest = wave-uniform base + lane*16
  __builtin_amdgcn_global_load_lds(
      (const __attribute__((address_space(1))) void*)gp,
      (__attribute__((address_space(3))) void*)lp, 16, 0, 0);
}

#define BAR()   __builtin_amdgcn_s_barrier()
#define SCB()   __builtin_amdgcn_sched_barrier(0)
#define LGKM0() asm volatile("s_waitcnt lgkmcnt(0)" ::: "memory")

// ---------------- fused prep: cast x, cast weights, rope tables ----------------
__global__ __launch_bounds__(256) void prep(
    const float* __restrict__ x,
    const float* __restrict__ wq, const float* __restrict__ wk,
    const float* __restrict__ wv, const float* __restrict__ wo,
    __bf16* __restrict__ xb, __bf16* __restrict__ wb,
    float* __restrict__ rc, float* __restrict__ rs) {
  const int b = blockIdx.x;
  if (b < 2048) {
    for (size_t i = (size_t)b * 256 + threadIdx.x; i < 8388608UL; i += 524288UL) {
      f32x4_t v = *(const f32x4_t*)&x[i * 4];
      bf16x4_t o;
      o[0] = (__bf16)v[0]; o[1] = (__bf16)v[1]; o[2] = (__bf16)v[2]; o[3] = (__bf16)v[3];
      *(bf16x4_t*)&xb[i * 4] = o;
    }
  } else if (b < 2304) {
    for (int i = (b - 2048) * 256 + threadIdx.x; i < 262144; i += 65536) {
      int which = i >> 16;
      int off   = (i & 65535) * 4;
      const float* src = (which == 0) ? wq : (which == 1) ? wk : (which == 2) ? wv : wo;
      f32x4_t v = *(const f32x4_t*)&src[off];
      bf16x4_t o;
      o[0] = (__bf16)v[0]; o[1] = (__bf16)v[1]; o[2] = (__bf16)v[2]; o[3] = (__bf16)v[3];
      *(bf16x4_t*)&wb[(size_t)which * 262144 + off] = o;
    }
  } else {
    int idx = (b - 2304) * 256 + threadIdx.x;
    if (idx < T_ * 32) {
      int t = idx >> 5, j = idx & 31;
      float inv = powf(10000.f, -(float)j * (1.0f / 32.0f));  // 10000^(-2j/64)
      float a = (float)t * inv;
      rc[idx] = cosf(a);
      rs[idx] = sinf(a);
    }
  }
}

// ---------------- 128x128 GEMM, BK=64, 4 waves, 8-phase schedule, T2 swizzle --
// Resized from the round-9-verified 256^2 template: 64 KiB LDS -> 2 blocks/CU so
// fill/drain/barrier stalls of one block hide under the other (K=512 gives only
// 8 K-tiles/block, so prologue+drain were ~20% exposed at 1 block/CU).
// Same regions {0:A.h0 1:B.h0 2:B.h1 3:A.h1}, same interleaved wave tiling
// (read-region == stage-region -> round-5 race proof carries over), same lead-7
// stage stream + vmcnt(6)/K-tile + setprio. Swizzle keys unchanged (row&7).
// MODE 0: 3 z-passes (Q,K,V), bf16 scatter to (B,H,T,hd), grid 6144 (z/N-fast).
// MODE 1: single pass, f32 row-major (m,512), grid 2048.
template <int MODE>
__global__ __launch_bounds__(256, 2) void gemm256(
    const __bf16* __restrict__ A, const __bf16* __restrict__ W,
    void* __restrict__ outp) {
  __shared__ __bf16 lds[32768];  // [dbuf2][mat2][128][64] bf16 = 64 KiB
  const int tid = threadIdx.x;
  const int lane = tid & 63, w = tid >> 6;    // 4 waves
  const int wm = w >> 1, wn = w & 1;          // 2 x 2 waves, wave tile 64x64 interleaved
  const int l15 = lane & 15, lg = lane >> 4;
  const int swl = l15 & 7;                    // read-side swizzle key (== row&7)

  // XCD-aware swizzle (grid % 8 == 0; 6144 or 2048)
  const int cpx = gridDim.x >> 3;
  const int swz = (blockIdx.x & 7) * cpx + (blockIdx.x >> 3);
  // z/N fastest: 12 consecutive swz (same XCD chunk) share one A-panel
  int m_idx, bz, bx;
  if (MODE == 0) {
    m_idx = swz / 12;
    const int rem = swz - m_idx * 12;
    bz = rem >> 2;
    bx = rem & 3;
  } else {
    m_idx = swz >> 2;
    bz = 0;
    bx = swz & 3;
  }
  const int m0 = m_idx * 128, n0 = bx * 128;

  const __bf16* Ag = A + (size_t)m0 * KDIM;
  const __bf16* Bg = W + (size_t)bz * (KDIM * KDIM) + (size_t)n0 * KDIM;
  const int srow = tid >> 3;          // 0..31
  // inverse swizzle on global source (gload_lds dest must stay linear)
  const int scol = (((tid & 7) ^ ((tid >> 3) & 7)) * 8);

  // stage half-tile J: tile T=J>>2, region r=J&3 (0:A.h0 1:B.h0 2:B.h1 3:A.h1)
  // region = 64 rows x 64 cols = 8KB; 256 threads x 16B x 2 gloads
#define STAGE(J) do {                                                        \
    const int T__ = (J) >> 2, r__ = (J) & 3;                                 \
    const int h__ = r__ >> 1;                                                \
    const int isB__ = (r__ == 1 || r__ == 2);                                \
    const size_t grow__ = (size_t)(h__ * 64 + srow) * KDIM + T__ * 64 + scol; \
    const __bf16* gp__ = isB__ ? (Bg + grow__) : (Ag + grow__);              \
    __bf16* lp__ = &lds[(T__ & 1) * 16384 + isB__ * 8192 + (h__ * 64 + w * 8) * 64]; \
    gload16(gp__, lp__);                                                     \
    gload16(gp__ + 32 * KDIM, lp__ + 32 * 64);                               \
  } while (0)

  f32x4_t acc[4][4];
#pragma unroll
  for (int i = 0; i < 4; i++)
#pragma unroll
    for (int j = 0; j < 4; j++) acc[i][j] = (f32x4_t){0.f, 0.f, 0.f, 0.f};

  bf16x8_t a0[2][2], a1[2][2], b0[2][2], b1[2][2];

  // phase macros: P = dbuf parity (literal), STJ = stage index or -1, VM = vmcnt
#define PH_A(P, STJ) do {                                                    \
    const int ab__ = (P) * 16384;                                            \
    _Pragma("unroll") for (int i = 0; i < 2; i++)                            \
      _Pragma("unroll") for (int s = 0; s < 2; s++)                          \
        a0[i][s] = *(const bf16x8_t*)&lds[ab__ + (wm * 32 + i * 16 + l15) * 64 + (((s * 4 + lg) ^ swl) << 3)]; \
    _Pragma("unroll") for (int j = 0; j < 2; j++)                            \
      _Pragma("unroll") for (int s = 0; s < 2; s++)                          \
        b0[j][s] = *(const bf16x8_t*)&lds[ab__ + 8192 + (wn * 32 + j * 16 + l15) * 64 + (((s * 4 + lg) ^ swl) << 3)]; \
    if ((STJ) >= 0) STAGE(STJ);                                              \
    SCB(); BAR(); LGKM0(); SCB();                                            \
    __builtin_amdgcn_s_setprio(1);                                           \
    _Pragma("unroll") for (int i = 0; i < 2; i++)                            \
      _Pragma("unroll") for (int j = 0; j < 2; j++) {                        \
        acc[i][j] = __builtin_amdgcn_mfma_f32_16x16x32_bf16(a0[i][0], b0[j][0], acc[i][j], 0, 0, 0); \
        acc[i][j] = __builtin_amdgcn_mfma_f32_16x16x32_bf16(a0[i][1], b0[j][1], acc[i][j], 0, 0, 0); \
      }                                                                      \
    __builtin_amdgcn_s_setprio(0); SCB(); BAR();                             \
  } while (0)

#define PH_B(P, STJ) do {                                                    \
    const int ab__ = (P) * 16384;                                            \
    _Pragma("unroll") for (int j = 0; j < 2; j++)                            \
      _Pragma("unroll") for (int s = 0; s < 2; s++)                          \
        b1[j][s] = *(const bf16x8_t*)&lds[ab__ + 8192 + (64 + wn * 32 + j * 16 + l15) * 64 + (((s * 4 + lg) ^ swl) << 3)]; \
    if ((STJ) >= 0) STAGE(STJ);                                              \
    SCB(); BAR(); LGKM0(); SCB();                                            \
    __builtin_amdgcn_s_setprio(1);                                           \
    _Pragma("unroll") for (int i = 0; i < 2; i++)                            \
      _Pragma("unroll") for (int j = 0; j < 2; j++) {                        \
        acc[i][j + 2] = __builtin_amdgcn_mfma_f32_16x16x32_bf16(a0[i][0], b1[j][0], acc[i][j + 2], 0, 0, 0); \
        acc[i][j + 2] = __builtin_amdgcn_mfma_f32_16x16x32_bf16(a0[i][1], b1[j][1], acc[i][j + 2], 0, 0, 0); \
      }                                                                      \
    __builtin_amdgcn_s_setprio(0); SCB(); BAR();                             \
  } while (0)

#define PH_C(P, STJ) do {                                                    \
    const int ab__ = (P) * 16384;                                            \
    _Pragma("unroll") for (int i = 0; i < 2; i++)                            \
      _Pragma("unroll") for (int s = 0; s < 2; s++)                          \
        a1[i][s] = *(const bf16x8_t*)&lds[ab__ + (64 + wm * 32 + i * 16 + l15) * 64 + (((s * 4 + lg) ^ swl) << 3)]; \
    if ((STJ) >= 0) STAGE(STJ);                                              \
    SCB(); BAR(); LGKM0(); SCB();                                            \
    __builtin_amdgcn_s_setprio(1);                                           \
    _Pragma("unroll") for (int i = 0; i < 2; i++)                            \
      _Pragma("unroll") for (int j = 0; j < 2; j++) {                        \
        acc[i + 2][j + 2] = __builtin_amdgcn_mfma_f32_16x16x32_bf16(a1[i][0], b1[j][0], acc[i + 2][j + 2], 0, 0, 0); \
        acc[i + 2][j + 2] = __builtin_amdgcn_mfma_f32_16x16x32_bf16(a1[i][1], b1[j][1], acc[i + 2][j + 2], 0, 0, 0); \
      }                                                                      \
    __builtin_amdgcn_s_setprio(0); SCB(); BAR();                             \
  } while (0)

#define PH_D(P, STJ, VM) do {                                                \
    if ((STJ) >= 0) STAGE(STJ);                                              \
    SCB(); BAR();                                                            \
    __builtin_amdgcn_s_setprio(1);                                           \
    _Pragma("unroll") for (int i = 0; i < 2; i++)                            \
      _Pragma("unroll") for (int j = 0; j < 2; j++) {                        \
        acc[i + 2][j] = __builtin_amdgcn_mfma_f32_16x16x32_bf16(a1[i][0], b0[j][0], acc[i + 2][j], 0, 0, 0); \
        acc[i + 2][j] = __builtin_amdgcn_mfma_f32_16x16x32_bf16(a1[i][1], b0[j][1], acc[i + 2][j], 0, 0, 0); \
      }                                                                      \
    __builtin_amdgcn_s_setprio(0);                                           \
    if ((VM) == 6) asm volatile("s_waitcnt vmcnt(6)" ::: "memory");          \
    else if ((VM) == 0) asm volatile("s_waitcnt vmcnt(0)" ::: "memory");     \
    SCB(); BAR();                                                            \
  } while (0)

  // prologue: stage S0..S6 (tile0 complete + tile1 r0,r1,r2)
  STAGE(0); STAGE(1); STAGE(2); STAGE(3); STAGE(4); STAGE(5); STAGE(6);
  asm volatile("s_waitcnt vmcnt(6)" ::: "memory");  // tile0 landed
  SCB(); BAR();

  // main: 8 K-tiles, stage lead 7 half-tiles, vmcnt(6) once per K-tile
#pragma unroll 1
  for (int tp = 0; tp < 3; ++tp) {
    const int g0 = tp * 8;
    PH_A(0, g0 + 7);  PH_B(0, g0 + 8);  PH_C(0, g0 + 9);  PH_D(0, g0 + 10, 6);
    PH_A(1, g0 + 11); PH_B(1, g0 + 12); PH_C(1, g0 + 13); PH_D(1, g0 + 14, 6);
  }
  PH_A(0, 31); PH_B(0, -1); PH_C(0, -1); PH_D(0, -1, 0);
  PH_A(1, -1); PH_B(1, -1); PH_C(1, -1); PH_D(1, -1, -1);

#undef PH_A
#undef PH_B
#undef PH_C
#undef PH_D
#undef STAGE

  // epilogue: C/D layout col=lane&15, row=(lane>>4)*4+reg  [m89-verified]
  // row: i<2 -> m0 + wm*32 + i*16 ; i>=2 -> +64. col: j<2 -> n0 + wn*32 + j*16 ; j>=2 -> +64.
#pragma unroll
  for (int i = 0; i < 4; i++) {
#pragma unroll
    for (int rr = 0; rr < 4; rr++) {
      const int m = m0 + (i >> 1) * 64 + wm * 32 + (i & 1) * 16 + lg * 4 + rr;
      if (MODE == 0) {
        __bf16* outz = (__bf16*)outp + (size_t)bz * ((size_t)BT_ * D_);
        const int bb = m >> 8, tt = m & 255;
        const size_t rbase = ((size_t)bb * H_) * T_ * HD_ + (size_t)tt * HD_;
#pragma unroll
        for (int j = 0; j < 4; j++) {
          const int c = n0 + (j >> 1) * 64 + wn * 32 + (j & 1) * 16 + l15;
          const int hh = c >> 6, dd = c & 63;
          outz[rbase + (size_t)hh * (T_ * HD_) + dd] = (__bf16)acc[i][j][rr];
        }
      } else {
        float* outf = (float*)outp;
#pragma unroll
        for (int j = 0; j < 4; j++) {
          const int c = n0 + (j >> 1) * 64 + wn * 32 + (j & 1) * 16 + l15;
          outf[(size_t)m * D_ + c] = acc[i][j][rr];
        }
      }
    }
  }
}

// ---------------- attention v4: swapped QK^T, wide P stores, fused norm+rope --
// (round-10 verified; byte-identical)
__global__ __launch_bounds__(512, 2) void attn_kernel(
    const __bf16* __restrict__ qb, const __bf16* __restrict__ kb,
    const __bf16* __restrict__ vb, __bf16* __restrict__ ob,
    const float* __restrict__ gq, const float* __restrict__ gk,
    const float* __restrict__ rc, const float* __restrict__ rs) {
  __shared__ __bf16 Kl[256 * 64];   // 32 KB
  __shared__ __bf16 VT[64 * 256];   // 32 KB (V transposed, d-major)
  __shared__ __bf16 Pl[8 * 16 * 64];// 16 KB (per-wave 64-key chunk, q-major)
  const int bh = blockIdx.x;
  const __bf16* Qg = qb + (size_t)bh * (T_ * HD_);
  const __bf16* Kg = kb + (size_t)bh * (T_ * HD_);
  const __bf16* Vg = vb + (size_t)bh * (T_ * HD_);
  const int tid = threadIdx.x, lane = tid & 63, w = tid >> 6;
  const int bI = bh >> 3, hI = bh & 7;

#pragma unroll
  for (int p = 0; p < 4; p++) {
    const int t = p * 64 + (tid >> 3);
    const int a = tid & 7;
    const int d0 = a * 8;
    // ---- K: load -> f32 -> RMSNorm -> RoPE -> bf16 -> swizzled LDS store ----
    bf16x8_t kv = *(const bf16x8_t*)&Kg[t * HD_ + d0];
    float kf[8], ss = 0.f;
#pragma unroll
    for (int j = 0; j < 8; j++) { kf[j] = (float)kv[j]; ss += kf[j] * kf[j]; }
    ss += __shfl_xor(ss, 1); ss += __shfl_xor(ss, 2); ss += __shfl_xor(ss, 4);
    const float rn = rsqrtf(ss * 0.015625f + 1e-6f);
    const f32x4_t gk0 = *(const f32x4_t*)&gk[d0];
    const f32x4_t gk1 = *(const f32x4_t*)&gk[d0 + 4];
    float vn[8];
#pragma unroll
    for (int j = 0; j < 8; j++) vn[j] = kf[j] * rn * ((j < 4) ? gk0[j] : gk1[j - 4]);
    float pn[8];
#pragma unroll
    for (int j = 0; j < 8; j++) pn[j] = __shfl_xor(vn[j], 4);  // rotate-half partner
    const int f0 = (a & 3) * 8;                                // freq base (d % 32)
    const f32x4_t c0 = *(const f32x4_t*)&rc[t * 32 + f0];
    const f32x4_t c1 = *(const f32x4_t*)&rc[t * 32 + f0 + 4];
    const f32x4_t s0 = *(const f32x4_t*)&rs[t * 32 + f0];
    const f32x4_t s1 = *(const f32x4_t*)&rs[t * 32 + f0 + 4];
    const float sg = (a < 4) ? -1.f : 1.f;
    bf16x8_t ko;
#pragma unroll
    for (int j = 0; j < 8; j++) {
      const float cc = (j < 4) ? c0[j] : c1[j - 4];
      const float sS = (j < 4) ? s0[j] : s1[j - 4];
      ko[j] = (__bf16)(vn[j] * cc + sg * pn[j] * sS);
    }
    *(bf16x8_t*)&Kl[t * 64 + (((a ^ (t & 7)) << 3))] = ko;
    // ---- V: plain transpose staging (unchanged) ----
    bf16x8_t vv = *(const bf16x8_t*)&Vg[t * HD_ + d0];
#pragma unroll
    for (int j = 0; j < 8; j++) {
      const int row = d0 + j;                       // V d-dim
      const int rk = (row & 7) ^ ((row >> 3) & 7);
      VT[row * 256 + (((t >> 3) ^ rk) << 3) + (t & 7)] = vv[j];
    }
  }
  __syncthreads();

  const int l15 = lane & 15;
  const int lg = lane >> 4;
  const int sw = l15 & 7;
  const f32x4_t zero = {0.f, 0.f, 0.f, 0.f};
  const float C1 = 0.0072134752f;      // 0.125 * 0.04 * log2(e)
  const float LOG2E = 1.44269504f;

  for (int half = 0; half < 2; half++) {
    const int qt = half ? (15 - w) : w;   // balanced: every wave ~18 even-tiles
    const int q0 = qt * 16;
    const int tq = q0 + l15;              // this lane's q-row (token index)
    // ---- Q: load -> f32 -> RMSNorm -> RoPE -> bf16 fragments (B-operand) ----
    bf16x8_t q0r = *(const bf16x8_t*)&Qg[tq * HD_ + lg * 8];
    bf16x8_t q1r = *(const bf16x8_t*)&Qg[tq * HD_ + 32 + lg * 8];
    float qf0[8], qf1[8], qss = 0.f;
#pragma unroll
    for (int j = 0; j < 8; j++) {
      qf0[j] = (float)q0r[j]; qf1[j] = (float)q1r[j];
      qss += qf0[j] * qf0[j] + qf1[j] * qf1[j];
    }
    qss += __shfl_xor(qss, 16); qss += __shfl_xor(qss, 32);
    const float qrn = rsqrtf(qss * 0.015625f + 1e-6f);
    const f32x4_t gqa = *(const f32x4_t*)&gq[lg * 8];
    const f32x4_t gqb2 = *(const f32x4_t*)&gq[lg * 8 + 4];
    const f32x4_t gqc = *(const f32x4_t*)&gq[32 + lg * 8];
    const f32x4_t gqd = *(const f32x4_t*)&gq[32 + lg * 8 + 4];
    const f32x4_t qc0 = *(const f32x4_t*)&rc[tq * 32 + lg * 8];
    const f32x4_t qc1 = *(const f32x4_t*)&rc[tq * 32 + lg * 8 + 4];
    const f32x4_t qs0 = *(const f32x4_t*)&rs[tq * 32 + lg * 8];
    const f32x4_t qs1 = *(const f32x4_t*)&rs[tq * 32 + lg * 8 + 4];
    bf16x8_t aq0, aq1;
#pragma unroll
    for (int j = 0; j < 8; j++) {
      const float glo = (j < 4) ? gqa[j] : gqb2[j - 4];
      const float ghi = (j < 4) ? gqc[j] : gqd[j - 4];
      const float cc  = (j < 4) ? qc0[j] : qc1[j - 4];
      const float sS  = (j < 4) ? qs0[j] : qs1[j - 4];
      const float vlo = qf0[j] * qrn * glo;
      const float vhi = qf1[j] * qrn * ghi;
      aq0[j] = (__bf16)(vlo * cc - vhi * sS);
      aq1[j] = (__bf16)(vhi * cc + vlo * sS);
    }

    const int ntiles_e = (qt + 2) & ~1;
    const int qr = q0 + (lg << 2);

    float ls = 0.f;
    f32x4_t o[4];
#pragma unroll
    for (int j = 0; j < 4; j++) o[j] = zero;

    for (int t0 = 0; t0 < ntiles_e; t0 += 4) {     // 64-key chunks
      const int te = (t0 + 4 < ntiles_e) ? (t0 + 4) : ntiles_e;
      for (int n = t0; n < te; ++n) {
        bf16x8_t kb0 = *(const bf16x8_t*)&Kl[(n * 16 + l15) * 64 + ((lg ^ sw) << 3)];
        bf16x8_t kb1 = *(const bf16x8_t*)&Kl[(n * 16 + l15) * 64 + (((4 + lg) ^ sw) << 3)];
        __builtin_amdgcn_s_setprio(1);
        f32x4_t a = __builtin_amdgcn_mfma_f32_16x16x32_bf16(kb0, aq0, zero, 0, 0, 0);
        a = __builtin_amdgcn_mfma_f32_16x16x32_bf16(kb1, aq1, a, 0, 0, 0);
        __builtin_amdgcn_s_setprio(0);
        const int kbase = n * 16 + (lg << 2);          // this lane's 4 keys
        bf16x4_t pk;
#pragma unroll
        for (int r = 0; r < 4; r++) {
          float e2 = __builtin_amdgcn_exp2f(a[r] * C1);
          float cm = -100.f * __builtin_amdgcn_rcpf(e2 + 1.f);  // cap - 50
          float p = __builtin_amdgcn_exp2f(cm * LOG2E);
          p = (kbase + r <= tq) ? p : 0.f;
          ls += p;
          pk[r] = (__bf16)p;
        }
        // one b64 store: row q=l15, logical 16B slot s16=2*nn+(lg>>1), half lg&1
        const int nn = n - t0;
        const int ph = (2 * nn + (lg >> 1)) ^ sw;
        *(bf16x4_t*)&Pl[w * 1024 + l15 * 64 + ph * 8 + (lg & 1) * 4] = pk;
      }
      asm volatile("s_waitcnt lgkmcnt(0)" ::: "memory");
      __builtin_amdgcn_sched_barrier(0);
      const int nkc = (te - t0) >> 1;
      for (int kcc = 0; kcc < nkc; ++kcc) {
        const int phr = (kcc * 4 + lg) ^ sw;           // read: one 16B slot
        bf16x8_t pa = *(const bf16x8_t*)&Pl[w * 1024 + l15 * 64 + phr * 8];
        __builtin_amdgcn_s_setprio(1);
#pragma unroll
        for (int j = 0; j < 4; j++) {
          const int row = j * 16 + l15;
          const int rk = sw ^ ((2 * j + (l15 >> 3)) & 7);   // VT key for this row
          const int sl = (t0 << 1) + kcc * 4 + lg;          // global 16B slot
          bf16x8_t bv = *(const bf16x8_t*)&VT[row * 256 + ((sl ^ rk) << 3)];
          o[j] = __builtin_amdgcn_mfma_f32_16x16x32_bf16(pa, bv, o[j], 0, 0, 0);
        }
        __builtin_amdgcn_s_setprio(0);
      }
    }

    // row-sum for q=l15: reduce over the 4 lane-groups
    ls += __shfl_xor(ls, 16);
    ls += __shfl_xor(ls, 32);
    const float inv = 1.0f / ls;
    float rl[4];
#pragma unroll
    for (int r = 0; r < 4; r++) rl[r] = __shfl(inv, (lg << 2) + r);

#pragma unroll
    for (int j = 0; j < 4; j++) {
      int dd = j * 16 + l15;
#pragma unroll
      for (int r = 0; r < 4; r++) {
        int q = qr + r;
        ob[((size_t)(bI * T_ + q)) * D_ + hI * HD_ + dd] = (__bf16)(o[j][r] * rl[r]);
      }
    }
  }
}

// ---------------- launch ----------------
extern "C" void kernel_launch(void* const* d_in, const int* in_sizes, int n_in,
                              void* d_out, int out_size, void* d_ws, size_t ws_size,
                              hipStream_t stream) {
  (void)in_sizes; (void)n_in; (void)out_size; (void)ws_size;
  const float* x  = (const float*)d_in[0];
  const float* wq = (const float*)d_in[1];
  const float* wk = (const float*)d_in[2];
  const float* wv = (const float*)d_in[3];
  const float* wo = (const float*)d_in[4];
  const float* gq = (const float*)d_in[5];
  const float* gk = (const float*)d_in[6];

  // ws layout (bytes): xb 64MB (aliased by attn-out) | q 64MB | k 64MB | v 64MB | w 2MB | rope 64KB
  char* ws = (char*)d_ws;
  __bf16* xb   = (__bf16*)ws;
  __bf16* qkvb = (__bf16*)(ws + 67108864UL);
  __bf16* qb = qkvb;
  __bf16* kb = qkvb + 33554432UL;
  __bf16* vb = qkvb + 67108864UL;
  __bf16* wb = (__bf16*)(ws + 4UL * 67108864UL);
  float*  rc = (float*)(ws + 4UL * 67108864UL + 2097152UL);
  float*  rs = rc + 8192;
  __bf16* ob = xb;  // alias: xb dead after QKV GEMM

  prep<<<dim3(2336), 256, 0, stream>>>(x, wq, wk, wv, wo, xb, wb, rc, rs);
  gemm256<0><<<dim3(6144), 256, 0, stream>>>(xb, wb, (void*)qkvb);
  attn_kernel<<<dim3(2048), 512, 0, stream>>>(qb, kb, vb, ob, gq, gk, rc, rs);
  gemm256<1><<<dim3(2048), 256, 0, stream>>>(ob, wb + 3UL * 262144UL, d_out);
}